// Round 8
// baseline (848.800 us; speedup 1.0000x reference)
//
#include <hip/hip_runtime.h>
#include <hip/hip_bf16.h>

typedef unsigned short u16;
typedef __attribute__((ext_vector_type(8))) short bh8;     // 8 bf16 (4 VGPRs)
typedef __attribute__((ext_vector_type(4))) float f32x4;   // MFMA acc

static __device__ __forceinline__ float b2fu(u16 u) {
    union { float f; unsigned int i; } x;
    x.i = ((unsigned int)u) << 16;
    return x.f;
}
static __device__ __forceinline__ u16 f2bu(float f) {
    __hip_bfloat16 h = __float2bfloat16(f);  // RNE
    union { __hip_bfloat16 h; u16 u; } x;
    x.h = h;
    return x.u;
}

// async global->LDS, 16B per lane; lds dest must be wave-uniform (HW adds lane*16)
static __device__ __forceinline__ void gload16(const u16* g, u16* l) {
    __builtin_amdgcn_global_load_lds(
        (const __attribute__((address_space(1))) unsigned int*)(const void*)g,
        (__attribute__((address_space(3))) unsigned int*)(void*)l, 16, 0, 0);
}

// ---------------- fallback ----------------

__global__ __launch_bounds__(256) void const_out_kernel(float* __restrict__ out, float v, int n) {
    int i = blockIdx.x * 256 + threadIdx.x;
    if (i < n) out[i] = v;
}

// ---------------- CSR build ----------------

__global__ __launch_bounds__(256) void hist2_kernel(const int* __restrict__ dst,
                                                    const int* __restrict__ batch,
                                                    int* __restrict__ hist,
                                                    int* __restrict__ ghist, int E, int N) {
    int i = blockIdx.x * 256 + threadIdx.x;
    if (i < E) atomicAdd(&hist[dst[i]], 1);
    else if (i < E + N) atomicAdd(&ghist[batch[i - E]], 1);
}

__global__ __launch_bounds__(256) void scan_tiles(const int* __restrict__ hist, int N,
                                                  int* __restrict__ rowptr,
                                                  int* __restrict__ tsum) {
    int tid = threadIdx.x;
    int i = blockIdx.x * 256 + tid;
    int v = (i < N) ? hist[i] : 0;
    __shared__ int s[256];
    s[tid] = v;
    __syncthreads();
    for (int off = 1; off < 256; off <<= 1) {
        int t = (tid >= off) ? s[tid - off] : 0;
        __syncthreads();
        s[tid] += t;
        __syncthreads();
    }
    if (i < N) rowptr[i] = s[tid] - v;
    if (tid == 255) tsum[blockIdx.x] = s[255];
}

// block 0: scan of tile sums (-> toff, total); block 1: graph-offset scan (ghist -> goff)
__global__ __launch_bounds__(256) void scan_misc(const int* __restrict__ tsum, int ntiles,
                                                 int* __restrict__ toff,
                                                 int* __restrict__ totalp,
                                                 const int* __restrict__ ghist,
                                                 int* __restrict__ goff,
                                                 int* __restrict__ gfill, int B) {
    int tid = threadIdx.x;
    if (blockIdx.x == 0) {
        int v = (tid < ntiles) ? tsum[tid] : 0;
        __shared__ int s[256];
        s[tid] = v;
        __syncthreads();
        for (int off = 1; off < 256; off <<= 1) {
            int t = (tid >= off) ? s[tid - off] : 0;
            __syncthreads();
            s[tid] += t;
            __syncthreads();
        }
        if (tid < ntiles) toff[tid] = s[tid] - v;
        if (tid == 255) *totalp = s[255];
    } else {
        int v = (tid < B) ? ghist[tid] : 0;
        __shared__ int s2[256];
        s2[tid] = v;
        __syncthreads();
        for (int off = 1; off < 256; off <<= 1) {
            int t = (tid >= off) ? s2[tid - off] : 0;
            __syncthreads();
            s2[tid] += t;
            __syncthreads();
        }
        if (tid < B) {
            goff[tid] = s2[tid] - v;
            gfill[tid] = s2[tid] - v;
        }
        if (tid == 255) goff[B] = s2[255];
    }
}

__global__ __launch_bounds__(256) void scan_apply(int* __restrict__ rowptr,
                                                  const int* __restrict__ toff, int N,
                                                  int* __restrict__ fill) {
    int i = blockIdx.x * 256 + threadIdx.x;
    if (i < N) {
        int r = rowptr[i] + toff[blockIdx.x];
        rowptr[i] = r;
        fill[i] = r;
    }
}

__global__ __launch_bounds__(256) void scatter_kernel(const int* __restrict__ src,
                                                      const int* __restrict__ dst,
                                                      int* __restrict__ fill,
                                                      int* __restrict__ srcs, int E) {
    int e = blockIdx.x * 256 + threadIdx.x;
    if (e < E) {
        int p = atomicAdd(&fill[dst[e]], 1);
        srcs[p] = src[e];
    }
}

// ---------------- GENConv aggregation -> bf16 A-operand (K-padded), VEC feats/thread ------

template <typename T, int VEC>
__global__ __launch_bounds__(256) void agg_kernel(const T* __restrict__ x,
                                                  const int* __restrict__ rowptr,
                                                  const int* __restrict__ srcs,
                                                  u16* __restrict__ out, int d, int ldx,
                                                  int Kp, int N) {
    int n = blockIdx.y * 4 + (threadIdx.x >> 6);
    int f0 = (blockIdx.x * 64 + (threadIdx.x & 63)) * VEC;
    if (n >= N || f0 >= Kp) return;
    size_t o = (size_t)n * Kp + f0;
    if (f0 >= d) {
#pragma unroll
        for (int i = 0; i < VEC; i++) out[o + i] = 0;
        return;
    }
    auto loadV = [&](const T* row, float* v) {
        if constexpr (sizeof(T) == 4) {
            float2 t = *reinterpret_cast<const float2*>(row);
            v[0] = t.x; v[1] = t.y;
        } else if constexpr (VEC == 2) {
            unsigned int u = *reinterpret_cast<const unsigned int*>(row);
            v[0] = b2fu((u16)(u & 0xffff)); v[1] = b2fu((u16)(u >> 16));
        } else if constexpr (VEC == 4) {
            uint2 u = *reinterpret_cast<const uint2*>(row);
            v[0] = b2fu((u16)(u.x & 0xffff)); v[1] = b2fu((u16)(u.x >> 16));
            v[2] = b2fu((u16)(u.y & 0xffff)); v[3] = b2fu((u16)(u.y >> 16));
        } else {
            uint4 u = *reinterpret_cast<const uint4*>(row);
            v[0] = b2fu((u16)(u.x & 0xffff)); v[1] = b2fu((u16)(u.x >> 16));
            v[2] = b2fu((u16)(u.y & 0xffff)); v[3] = b2fu((u16)(u.y >> 16));
            v[4] = b2fu((u16)(u.z & 0xffff)); v[5] = b2fu((u16)(u.z >> 16));
            v[6] = b2fu((u16)(u.w & 0xffff)); v[7] = b2fu((u16)(u.w >> 16));
        }
    };
    int e0 = rowptr[n], e1 = rowptr[n + 1];
    float s[VEC] = {}, t[VEC] = {};
    for (int e = e0; e < e1; e++) {
        int sr = srcs[e];
        float v[VEC];
        loadV(x + (size_t)sr * ldx + f0, v);
#pragma unroll
        for (int i = 0; i < VEC; i++) {
            float m = fmaxf(v[i], 0.f) + 1e-7f;
            float wv = __expf(m);
            s[i] += wv;
            t[i] += m * wv;
        }
    }
    float xs[VEC];
    loadV(x + (size_t)n * ldx + f0, xs);
    u16 ob[VEC];
#pragma unroll
    for (int i = 0; i < VEC; i++) {
        float a = t[i] / (s[i] + 1e-16f) + xs[i];
        ob[i] = (f0 + i < d) ? f2bu(a) : (u16)0;
    }
    if constexpr (VEC == 2) {
        *reinterpret_cast<unsigned int*>(out + o) =
            (unsigned int)ob[0] | ((unsigned int)ob[1] << 16);
    } else if constexpr (VEC == 4) {
        uint2 u;
        u.x = (unsigned int)ob[0] | ((unsigned int)ob[1] << 16);
        u.y = (unsigned int)ob[2] | ((unsigned int)ob[3] << 16);
        *reinterpret_cast<uint2*>(out + o) = u;
    } else {
        uint4 u;
        u.x = (unsigned int)ob[0] | ((unsigned int)ob[1] << 16);
        u.y = (unsigned int)ob[2] | ((unsigned int)ob[3] << 16);
        u.z = (unsigned int)ob[4] | ((unsigned int)ob[5] << 16);
        u.w = (unsigned int)ob[6] | ((unsigned int)ob[7] << 16);
        *reinterpret_cast<uint4*>(out + o) = u;
    }
}

// ---------------- batched weight transpose+cvt: W[K,N] f32 -> WT[Np,Kp] bf16 ----------------

struct WtJobs {
    const float* W[6];
    u16* WT[6];
    int K[6], N[6], Kp[6], Np[6];
};

__global__ __launch_bounds__(256) void wt_cvt6(WtJobs jb) {
    int jz = blockIdx.z;
    int Kp = jb.Kp[jz], Np = jb.Np[jz];
    int n = blockIdx.y * 4 + (threadIdx.x >> 6);
    int k = blockIdx.x * 64 + (threadIdx.x & 63);
    if (n >= Np || k >= Kp) return;
    int K = jb.K[jz], N = jb.N[jz];
    float v = (n < N && k < K) ? jb.W[jz][(size_t)k * N + n] : 0.f;
    jb.WT[jz][(size_t)n * Kp + k] = f2bu(v);
}

// ---------------- MFMA GEMM, fused variants ----------------
// Base: XCD swizzle, BK=32, 2 LDS buffers, minimal 2-phase. Column 16B-slots
// XOR-swizzled by ((row>>1)&3) on both sides.
// AMODE 0: A staged via global_load_lds.
// AMODE 1: A reg-staged with BN(scale/shift)+relu applied in-flight; scale/shift are
//          COMPUTED IN-KERNEL from sum/sumsq/gamma/beta into LDS (replaces bn_final).
// EMODE 0: plain epilogue (bias [+relu]); zero-fills pad cols Ncols<=n<ldc.
// EMODE 1: BN-stats epilogue: K-padded C + per-column sum/sumsq atomics.

template <int AMODE, int EMODE, bool RELU, typename CT>
__global__ __launch_bounds__(256) void gemm_mfma(const u16* __restrict__ A,
                                                 const u16* __restrict__ BT,
                                                 const float* __restrict__ bias,
                                                 CT* __restrict__ C, int ldc, int M, int Ncols,
                                                 int Kp, int nbx, int nby, int spx,
                                                 const float* __restrict__ bnsum,
                                                 const float* __restrict__ bnsumsq,
                                                 const float* __restrict__ gamma,
                                                 const float* __restrict__ beta,
                                                 float invN, int dhBN,
                                                 float* __restrict__ osum,
                                                 float* __restrict__ osumsq) {
    int xcd = blockIdx.x & 7;
    int j = blockIdx.x >> 3;
    int bx = j % nbx;
    int by = xcd * spx + j / nbx;
    if (by >= nby) return;
    __shared__ u16 As[2][128 * 32];
    __shared__ u16 Bs[2][128 * 32];
    __shared__ float scl[AMODE == 1 ? 640 : 1];
    __shared__ float shf[AMODE == 1 ? 640 : 1];
    const int tid = threadIdx.x;
    const int lane = tid & 63;
    const int w = tid >> 6;
    const int bm = by * 128;
    const int bn = bx * 128;
    f32x4 acc[4][4] = {};

    if constexpr (AMODE == 1) {  // in-kernel bn_final (redundant per block, trivial)
        for (int i = tid; i < Kp; i += 256) {
            float sc = 0.f, sh = 0.f;
            if (i < dhBN) {
                float mu = bnsum[i] * invN;
                float var = bnsumsq[i] * invN - mu * mu;
                sc = gamma[i] / sqrtf(var + 1e-5f);
                sh = beta[i] - mu * sc;
            }
            scl[i] = sc;
            shf[i] = sh;
        }
        __syncthreads();
    }

    const int r0 = w * 16 + (lane >> 2);
    const int r1 = r0 + 64;                       // sigma(r1) == sigma(r0)
    const int sw = ((lane & 3) ^ ((r0 >> 1) & 3)) << 3;  // u16 offset of source col
    const u16* Ag0 = A + (size_t)(bm + r0) * Kp + sw;
    const u16* Ag1 = A + (size_t)(bm + r1) * Kp + sw;
    const u16* Bg0 = BT + (size_t)(bn + r0) * Kp + sw;
    const u16* Bg1 = BT + (size_t)(bn + r1) * Kp + sw;
    const int wb = w << 9;  // wave LDS base (u16 units): w*1024B

    uint4 a0r, a1r;  // AMODE1 in-flight A regs
    auto stageB = [&](int b, int koff) {
        gload16(Bg0 + koff, &Bs[b][wb]);
        gload16(Bg1 + koff, &Bs[b][2048 + wb]);
    };
    auto stageA_lds = [&](int b, int koff) {
        gload16(Ag0 + koff, &As[b][wb]);
        gload16(Ag1 + koff, &As[b][2048 + wb]);
    };
    auto loadA_reg = [&](int koff) {
        a0r = *reinterpret_cast<const uint4*>(Ag0 + koff);
        a1r = *reinterpret_cast<const uint4*>(Ag1 + koff);
    };
    auto writeA_reg = [&](int b, int koff) {
        int f0 = sw + koff;  // feature (=source col) index of this lane's 8 elems
        float4 sc0 = *reinterpret_cast<const float4*>(&scl[f0]);
        float4 sc1 = *reinterpret_cast<const float4*>(&scl[f0 + 4]);
        float4 sh0 = *reinterpret_cast<const float4*>(&shf[f0]);
        float4 sh1 = *reinterpret_cast<const float4*>(&shf[f0 + 4]);
        auto tf2 = [](unsigned int u, float sa, float sb, float ha, float hb) {
            float h0 = b2fu((u16)(u & 0xffff)), h1 = b2fu((u16)(u >> 16));
            float v0 = fmaxf(fmaf(h0, sa, ha), 0.f);
            float v1 = fmaxf(fmaf(h1, sb, hb), 0.f);
            return (unsigned int)f2bu(v0) | ((unsigned int)f2bu(v1) << 16);
        };
        uint4 o0, o1;
        o0.x = tf2(a0r.x, sc0.x, sc0.y, sh0.x, sh0.y);
        o0.y = tf2(a0r.y, sc0.z, sc0.w, sh0.z, sh0.w);
        o0.z = tf2(a0r.z, sc1.x, sc1.y, sh1.x, sh1.y);
        o0.w = tf2(a0r.w, sc1.z, sc1.w, sh1.z, sh1.w);
        o1.x = tf2(a1r.x, sc0.x, sc0.y, sh0.x, sh0.y);
        o1.y = tf2(a1r.y, sc0.z, sc0.w, sh0.z, sh0.w);
        o1.z = tf2(a1r.z, sc1.x, sc1.y, sh1.x, sh1.y);
        o1.w = tf2(a1r.w, sc1.z, sc1.w, sh1.z, sh1.w);
        *reinterpret_cast<uint4*>(&As[b][wb + lane * 8]) = o0;
        *reinterpret_cast<uint4*>(&As[b][2048 + wb + lane * 8]) = o1;
    };

    // fragment read geometry (XOR involution cancels against the staged layout)
    const int fm = (w >> 1) * 64 + (lane & 15);
    const int fn = (w & 1) * 64 + (lane & 15);
    const int g = lane >> 4;
    const int ka = (g ^ ((fm >> 1) & 3)) << 3;  // sigma(fm+mt*16)==sigma(fm)
    const int kb = (g ^ ((fn >> 1) & 3)) << 3;

    const int nk = Kp >> 5;
    // prologue: stage tile 0, drain, barrier
    if constexpr (AMODE == 0) {
        stageA_lds(0, 0);
        stageB(0, 0);
        asm volatile("s_waitcnt vmcnt(0)" ::: "memory");
    } else {
        loadA_reg(0);
        stageB(0, 0);
        asm volatile("s_waitcnt vmcnt(0)" ::: "memory");
        writeA_reg(0, 0);
        asm volatile("s_waitcnt lgkmcnt(0)" ::: "memory");
    }
    __builtin_amdgcn_s_barrier();
    for (int k = 0; k < nk; k++) {
        const int cur = k & 1;
        if (k + 1 < nk) {  // prefetch next tile
            if constexpr (AMODE == 0) stageA_lds(cur ^ 1, (k + 1) << 5);
            else loadA_reg((k + 1) << 5);
            stageB(cur ^ 1, (k + 1) << 5);
        }
        bh8 af[4], bf[4];
#pragma unroll
        for (int mt = 0; mt < 4; mt++)
            af[mt] = *reinterpret_cast<const bh8*>(&As[cur][(fm + mt * 16) * 32 + ka]);
#pragma unroll
        for (int nt = 0; nt < 4; nt++)
            bf[nt] = *reinterpret_cast<const bh8*>(&Bs[cur][(fn + nt * 16) * 32 + kb]);
        asm volatile("s_waitcnt lgkmcnt(0)" ::: "memory");
        __builtin_amdgcn_sched_barrier(0);  // rule #18: don't hoist MFMA above the wait
        __builtin_amdgcn_s_setprio(1);
#pragma unroll
        for (int mt = 0; mt < 4; mt++)
#pragma unroll
            for (int nt = 0; nt < 4; nt++)
                acc[mt][nt] = __builtin_amdgcn_mfma_f32_16x16x32_bf16(af[mt], bf[nt],
                                                                      acc[mt][nt], 0, 0, 0);
        __builtin_amdgcn_s_setprio(0);
        __builtin_amdgcn_sched_barrier(0);  // keep MFMAs above the drain
        asm volatile("s_waitcnt vmcnt(0)" ::: "memory");  // next tile's loads landed
        if constexpr (AMODE == 1) {
            __builtin_amdgcn_sched_barrier(0);
            if (k + 1 < nk) writeA_reg(cur ^ 1, (k + 1) << 5);
            asm volatile("s_waitcnt lgkmcnt(0)" ::: "memory");  // ds_writes visible
        }
        __builtin_amdgcn_s_barrier();  // all waves: reads of cur done, nxt ready
    }
    const int rq = (lane >> 4) * 4;
    const int cl = lane & 15;
    if constexpr (EMODE == 0) {
#pragma unroll
        for (int mt = 0; mt < 4; mt++) {
#pragma unroll
            for (int nt = 0; nt < 4; nt++) {
                int n = bn + (w & 1) * 64 + nt * 16 + cl;
                if (n >= ldc) continue;
                bool valid = (n < Ncols);
                float bv = valid ? bias[n] : 0.f;
#pragma unroll
                for (int r = 0; r < 4; r++) {
                    int m = bm + (w >> 1) * 64 + mt * 16 + rq + r;
                    if (m >= M) continue;
                    float v = valid ? acc[mt][nt][r] + bv : 0.f;
                    if (RELU) v = fmaxf(v, 0.f);
                    if (sizeof(CT) == 2)
                        C[(size_t)m * ldc + n] = (CT)f2bu(v);
                    else
                        C[(size_t)m * ldc + n] = (CT)v;
                }
            }
        }
    } else {
        // BN-stats epilogue
        float cs[4] = {0.f, 0.f, 0.f, 0.f}, cq[4] = {0.f, 0.f, 0.f, 0.f};
#pragma unroll
        for (int nt = 0; nt < 4; nt++) {
            int n = bn + (w & 1) * 64 + nt * 16 + cl;
            if (n >= ldc) continue;
            float bv = (n < Ncols) ? bias[n] : 0.f;
#pragma unroll
            for (int mt = 0; mt < 4; mt++) {
#pragma unroll
                for (int r = 0; r < 4; r++) {
                    int m = bm + (w >> 1) * 64 + mt * 16 + rq + r;
                    if (m >= M) continue;
                    float v = (n < Ncols) ? acc[mt][nt][r] + bv : 0.f;
                    C[(size_t)m * ldc + n] = (CT)f2bu(v);
                    cs[nt] += v;
                    cq[nt] += v * v;
                }
            }
        }
        float* red = (float*)&As[0][0];  // 128 cols x 8 slots x {sum,sq} = 8 KB
        const int slot = (w >> 1) * 4 + (lane >> 4);
#pragma unroll
        for (int nt = 0; nt < 4; nt++) {
            int nl = (w & 1) * 64 + nt * 16 + cl;
            red[nl * 8 + slot] = cs[nt];
            red[1024 + nl * 8 + slot] = cq[nt];
        }
        __syncthreads();
        if (tid < 128) {
            int n = bn + tid;
            if (n < Ncols) {
                float s = 0.f, q = 0.f;
#pragma unroll
                for (int i = 0; i < 8; i++) {
                    s += red[tid * 8 + i];
                    q += red[1024 + tid * 8 + i];
                }
                atomicAdd(&osum[n], s);
                atomicAdd(&osumsq[n], q);
            }
        }
    }
}

// ---------------- segmented global mean pool (batch sorted) ----------------

__global__ __launch_bounds__(256) void pool_seg(const u16* __restrict__ h,
                                                const int* __restrict__ goff,
                                                float* __restrict__ gsum, int d) {
    int g = blockIdx.y;
    int c = threadIdx.x & 63;
    int f = blockIdx.x * 64 + c;
    int wv = threadIdx.x >> 6;
    int r0 = goff[g], r1 = goff[g + 1];
    float s = 0.f;
    if (f < d)
        for (int r = r0 + wv; r < r1; r += 4) s += b2fu(h[(size_t)r * d + f]);
    __shared__ float ls[4][64];
    ls[wv][c] = s;
    __syncthreads();
    if (wv == 0 && f < d) {
        float tot = ls[0][c] + ls[1][c] + ls[2][c] + ls[3][c];
        gsum[(size_t)g * d + f] = tot / fmaxf((float)(r1 - r0), 1.f);
    }
}

// ---------------- split-K GEMM for small-M FC chain (f32) ----------------
// C pre-filled with bias; relu applied to A elements with k < klim.

__global__ __launch_bounds__(256) void gemm_sk(const float* __restrict__ A, int lda,
                                               const float* __restrict__ B, int ldb,
                                               float* __restrict__ C, int ldc, int M, int K,
                                               int Nn, int KC, int klim) {
    __shared__ float As[16][17];
    __shared__ float Bs[16][68];
    const int tid = threadIdx.x;
    const int bn = blockIdx.x * 64;
    const int bm = blockIdx.y * 16;
    const int k0 = blockIdx.z * KC;
    const int kend = min(K, k0 + KC);
    const int tx = tid & 63;
    const int ty = tid >> 6;
    float acc[4] = {};
    const int am = bm + (tid >> 4);
    const int ak = tid & 15;
    for (int kk0 = k0; kk0 < kend; kk0 += 16) {
        {
            int k = kk0 + ak;
            float v = (am < M && k < kend) ? A[(size_t)am * lda + k] : 0.f;
            if (k < klim) v = fmaxf(v, 0.f);
            As[ak][tid >> 4] = v;
        }
#pragma unroll
        for (int i = 0; i < 4; i++) {
            int k = kk0 + ty + 4 * i;
            Bs[ty + 4 * i][tx] = (k < kend && bn + tx < Nn) ? B[(size_t)k * ldb + bn + tx] : 0.f;
        }
        __syncthreads();
#pragma unroll
        for (int kk = 0; kk < 16; kk++) {
            float b = Bs[kk][tx];
#pragma unroll
            for (int i = 0; i < 4; i++) acc[i] = fmaf(As[kk][ty + 4 * i], b, acc[i]);
        }
        __syncthreads();
    }
    if (bn + tx < Nn) {
#pragma unroll
        for (int i = 0; i < 4; i++) {
            int m = bm + ty + 4 * i;
            if (m < M) atomicAdd(&C[(size_t)m * ldc + bn + tx], acc[i]);
        }
    }
}

static void launch_gemm_small(const float* A, int lda, const float* B, int ldb,
                              float* C, int ldc, int M, int K, int Nn, int klim,
                              hipStream_t stream) {
    int gx = (Nn + 63) / 64, gy = (M + 15) / 16;
    int tiles = gx * gy;
    int ksplit = 512 / tiles;
    if (ksplit < 1) ksplit = 1;
    int maxsplit = (K + 63) / 64;
    if (ksplit > maxsplit) ksplit = maxsplit;
    int KC = (((K + ksplit - 1) / ksplit) + 15) & ~15;
    ksplit = (K + KC - 1) / KC;
    gemm_sk<<<dim3(gx, gy, ksplit), 256, 0, stream>>>(A, lda, B, ldb, C, ldc, M, K, Nn, KC,
                                                      klim);
}

// ---------------- batched bias prefill for FC output buffers ----------------

struct FillJobs {
    float* C[6];
    const float* b[6];
    int ld[6], n0[6], n1[6];
};

__global__ __launch_bounds__(256) void prefill6(FillJobs jb, int M) {
    int jz = blockIdx.z;
    int w = jb.n1[jz] - jb.n0[jz];
    int i = blockIdx.x * 256 + threadIdx.x;
    if (i >= M * w) return;
    int m = i / w, n = i - m * w;
    jb.C[jz][(size_t)m * jb.ld[jz] + jb.n0[jz] + n] = jb.b[jz][n];
}

// ---------------- fused protein branch: one block per graph ----------------
// S[t][o*8+k] = sum_{i: target[b,i]==t} cw[o,i,k]  (LDS, f32, race-free: thread owns (o,k))
// conv[o,w]   = cb[o] + sum_t sum_k S[t][o*8+k] * emb[t*128+w+k]
// xt[n]       = sum_j conv_flat[j] * fxtw[j*128+n] + fxtb[n]  -> xc[b][128+n]
// Replaces: Hbuf memset, hone, cwt_cvt, Sbuf memset, S-GEMM, prot_conv, fxt gemm_sk.

__global__ __launch_bounds__(256) void prot_fused(const int* __restrict__ target,
                                                  const float* __restrict__ cw,
                                                  const float* __restrict__ emb,
                                                  const float* __restrict__ cb,
                                                  const float* __restrict__ fxtw,
                                                  const float* __restrict__ fxtb,
                                                  float* __restrict__ xc) {
    int b = blockIdx.x;
    int tid = threadIdx.x;
    __shared__ float Sl[26 * 256];   // 26.6 KB
    __shared__ float el[26 * 128];   // 13.3 KB
    __shared__ int tl[1000];         //  4.0 KB
    __shared__ float cv[3872];       // 15.5 KB
    __shared__ float xs[128];
    for (int i = tid; i < 26 * 256; i += 256) Sl[i] = 0.f;
    for (int i = tid; i < 26 * 128; i += 256) el[i] = emb[i];
    for (int i = tid; i < 1000; i += 256) tl[i] = target[(size_t)b * 1000 + i];
    __syncthreads();
    {
        int o = tid >> 3, k = tid & 7;
        const float* cwp = cw + (size_t)o * 8000 + k;
        for (int i = 0; i < 1000; i++) {
            int t = tl[i];
            Sl[t * 256 + tid] += cwp[(size_t)i * 8];
        }
    }
    __syncthreads();
    for (int j = tid; j < 3872; j += 256) {
        int o = j / 121;
        int w = j - o * 121;
        float acc = cb[o];
        for (int t = 0; t < 26; t++)
#pragma unroll
            for (int k = 0; k < 8; k++)
                acc = fmaf(Sl[t * 256 + o * 8 + k], el[t * 128 + w + k], acc);
        cv[j] = acc;
    }
    __syncthreads();
    {
        int n = tid & 127, half = tid >> 7;
        float acc = 0.f;
        int j0 = half * 1936, j1 = j0 + 1936;
#pragma unroll 4
        for (int j = j0; j < j1; j++) acc = fmaf(cv[j], fxtw[(size_t)j * 128 + n], acc);
        if (half == 1) xs[n] = acc;
        __syncthreads();
        if (half == 0) xc[(size_t)b * 256 + 128 + n] = acc + xs[n] + fxtb[n];
    }
}

// ---------------- final matvec (relu on A load) ----------------

__global__ __launch_bounds__(256) void out_kernel(const float* __restrict__ A,
                                                  const float* __restrict__ w,
                                                  const float* __restrict__ bias,
                                                  float* __restrict__ out, int M, int K) {
    int wave = threadIdx.x >> 6;
    int lane = threadIdx.x & 63;
    int r = blockIdx.x * 4 + wave;
    if (r >= M) return;
    float acc = 0.f;
    for (int k = lane; k < K; k += 64) acc += fmaxf(A[(size_t)r * K + k], 0.f) * w[k];
    for (int off = 32; off > 0; off >>= 1) acc += __shfl_down(acc, off, 64);
    if (lane == 0) out[r] = acc + bias[0];
}

// ---------------- host orchestration ----------------

static inline int KP(int k) { return (k + 31) & ~31; }
static inline int NP(int n) { return (n + 127) & ~127; }
static inline int LD8(int n) { return (n + 7) & ~7; }

extern "C" void kernel_launch(void* const* d_in, const int* in_sizes, int n_in, void* d_out,
                              int out_size, void* d_ws, size_t ws_size, hipStream_t stream) {
    static const int exp_sizes[39] = {
        2340000, 300000, 30000, 256000,
        12168, 156, 156, 156, 12168, 78,
        12168, 156, 156, 156, 48672, 312,
        194688, 624, 624, 624, 389376, 624,
        319488, 512, 524288, 1024, 131072, 128,
        3328, 256000, 32, 495616, 128,
        262144, 1024, 524288, 512, 512, 1};
    int bad = (n_in != 39) ? 100 : -1;
    if (bad < 0)
        for (int i = 0; i < 39; i++)
            if (in_sizes[i] != exp_sizes[i]) { bad = i; break; }
    if (bad >= 0) {
        const_out_kernel<<<1, 256, 0, stream>>>((float*)d_out, 2048.f + 8.f * bad, out_size);
        return;
    }

    const int N = 30000, E = 150000, B = 256;
    const int Mp = 30080;   // 235*128
    const int nby = 235, spx = 30;
    const int ntiles = (N + 255) / 256;  // 118
    const float* x_in = (const float*)d_in[0];
    const int* ei = (const int*)d_in[1];
    const int* src = ei;
    const int* dst = ei + E;
    const int* batch = (const int*)d_in[2];
    const int* target = (const int*)d_in[3];

    char* p = (char*)d_ws;
    auto carve = [&](size_t bytes) {
        char* r = p;
        p += (bytes + 15) & ~(size_t)15;
        return r;
    };
    // hist + ghist + per-layer BN sums: one contiguous zero region
    int* hist = (int*)carve((size_t)(N + B) * 4 + 3 * 1280 * 4);
    int* ghist = hist + N;
    float* sums = (float*)(hist + N + B);  // 3 layers x {sum[640], sumsq[640]}
    const size_t zero_bytes = (size_t)(N + B) * 4 + 3 * 1280 * 4;
    int* rowptr = (int*)carve((size_t)(N + 1) * 4);
    int* fill = (int*)carve((size_t)N * 4);
    int* srcs = (int*)carve((size_t)E * 4);
    int* goff = (int*)carve((size_t)(B + 1) * 4);
    int* gfill = (int*)carve((size_t)B * 4);
    int* tsum = (int*)carve(256 * 4);
    int* toff = (int*)carve(256 * 4);
    float* gsum = (float*)carve((size_t)B * 624 * 4);
    float* fc1 = (float*)carve((size_t)B * 512 * 4);
    float* fc2 = (float*)carve((size_t)B * 1024 * 4);
    float* xc = (float*)carve((size_t)B * 256 * 4);
    float* fcc1 = (float*)carve((size_t)B * 1024 * 4);
    float* fcc2 = (float*)carve((size_t)B * 512 * 4);
    u16* Abf = (u16*)carve((size_t)Mp * 640 * 2);
    u16* hmidb = (u16*)carve((size_t)Mp * 640 * 2);   // K-padded h (GEMM2 A operand)
    u16* Lout = (u16*)carve((size_t)N * 624 * 2);
    struct Layer { int di, dh, dn, w1, b1, g, be, w2, b2; };
    const Layer L[3] = {
        {78, 156, 78, 4, 5, 6, 7, 8, 9},
        {78, 156, 312, 10, 11, 12, 13, 14, 15},
        {312, 624, 624, 16, 17, 18, 19, 20, 21},
    };
    u16* WT1[3];
    u16* WT2[3];
    for (int li = 0; li < 3; li++) {
        WT1[li] = (u16*)carve((size_t)NP(L[li].dh) * KP(L[li].di) * 2);
        WT2[li] = (u16*)carve((size_t)NP(L[li].dn) * KP(L[li].dh) * 2);
    }
    size_t need = (size_t)(p - (char*)d_ws);
    if (ws_size < need) {
        const_out_kernel<<<1, 256, 0, stream>>>((float*)d_out,
                                                1024.f + (float)(ws_size >> 20), out_size);
        return;
    }

    // ---- CSR by dst (hierarchical scan) + graph offsets ----
    hipMemsetAsync(hist, 0, zero_bytes, stream);
    hist2_kernel<<<(E + N + 255) / 256, 256, 0, stream>>>(dst, batch, hist, ghist, E, N);
    scan_tiles<<<ntiles, 256, 0, stream>>>(hist, N, rowptr, tsum);
    scan_misc<<<2, 256, 0, stream>>>(tsum, ntiles, toff, rowptr + N, ghist, goff, gfill, B);
    scan_apply<<<ntiles, 256, 0, stream>>>(rowptr, toff, N, fill);
    scatter_kernel<<<(E + 255) / 256, 256, 0, stream>>>(src, dst, fill, srcs, E);

    // ---- weight transpose+cvt (single batched dispatch) ----
    {
        WtJobs jb;
        int mgx = 1, mgy = 1;
        for (int li = 0; li < 3; li++) {
            jb.W[2 * li] = (const float*)d_in[L[li].w1];
            jb.WT[2 * li] = WT1[li];
            jb.K[2 * li] = L[li].di; jb.N[2 * li] = L[li].dh;
            jb.Kp[2 * li] = KP(L[li].di); jb.Np[2 * li] = NP(L[li].dh);
            jb.W[2 * li + 1] = (const float*)d_in[L[li].w2];
            jb.WT[2 * li + 1] = WT2[li];
            jb.K[2 * li + 1] = L[li].dh; jb.N[2 * li + 1] = L[li].dn;
            jb.Kp[2 * li + 1] = KP(L[li].dh); jb.Np[2 * li + 1] = NP(L[li].dn);
        }
        for (int i = 0; i < 6; i++) {
            int gx = (jb.Kp[i] + 63) / 64, gy = jb.Np[i] / 4;
            if (gx > mgx) mgx = gx;
            if (gy > mgy) mgy = gy;
        }
        wt_cvt6<<<dim3(mgx, mgy, 6), 256, 0, stream>>>(jb);
    }

    // ---- GENConv layers (BN stats fused into GEMM1, bn_final+BN apply fused into GEMM2) --
    const int ldo[3] = {LD8(L[0].dn), LD8(L[1].dn), LD8(L[2].dn)};  // 80, 312, 624
    for (int li = 0; li < 3; li++) {
        const int di = L[li].di, dh = L[li].dh, dn = L[li].dn;
        const int Kp1 = KP(di), Kp2 = KP(dh);
        float* sumL = sums + li * 1280;
        float* sumsqL = sumL + 640;
        if (li == 0)
            agg_kernel<float, 2><<<dim3((Kp1 / 2 + 63) / 64, (N + 3) / 4), 256, 0, stream>>>(
                x_in, rowptr, srcs, Abf, di, di, Kp1, N);
        else if (li == 1)
            agg_kernel<u16, 4><<<dim3((Kp1 / 4 + 63) / 64, (N + 3) / 4), 256, 0, stream>>>(
                Lout, rowptr, srcs, Abf, di, ldo[0], Kp1, N);
        else
            agg_kernel<u16, 8><<<dim3((Kp1 / 8 + 63) / 64, (N + 3) / 4), 256, 0, stream>>>(
                Lout, rowptr, srcs, Abf, di, ldo[1], Kp1, N);
        {
            // h = Abf @ W1 + b1 -> hmidb (ldc = Kp2, zero-padded cols) + column stats
            int nbx = NP(dh) / 128;
            gemm_mfma<0, 1, false, u16><<<dim3(8 * spx * nbx), 256, 0, stream>>>(
                Abf, WT1[li], (const float*)d_in[L[li].b1], hmidb, Kp2, N, dh, Kp1, nbx, nby,
                spx, nullptr, nullptr, nullptr, nullptr, 0.f, 0, sumL, sumsqL);
        }
        {
            // Lout = relu(bn(h)) @ W2 + b2; scale/shift computed in-kernel from stats
            int nbx = NP(dn) / 128;
            gemm_mfma<1, 0, true, u16><<<dim3(8 * spx * nbx), 256, 0, stream>>>(
                hmidb, WT2[li], (const float*)d_in[L[li].b2], Lout, ldo[li], N, dn, Kp2, nbx,
                nby, spx, sumL, sumsqL, (const float*)d_in[L[li].g],
                (const float*)d_in[L[li].be], 1.0f / N, dh, nullptr, nullptr);
        }
    }

    // ---- segmented global mean pool (Lout stride 624 == d) ----
    pool_seg<<<dim3(10, B), 256, 0, stream>>>(Lout, goff, gsum, 624);

    // ---- FC output buffers: prefill with bias ----
    {
        FillJobs fj;
        fj.C[0] = fc1;  fj.b[0] = (const float*)d_in[23]; fj.ld[0] = 512;  fj.n0[0] = 0; fj.n1[0] = 512;
        fj.C[1] = fc2;  fj.b[1] = (const float*)d_in[25]; fj.ld[1] = 1024; fj.n0[1] = 0; fj.n1[1] = 1024;
        fj.C[2] = xc;   fj.b[2] = (const float*)d_in[27]; fj.ld[2] = 256;  fj.n0[2] = 0; fj.n1[2] = 128;
        fj.C[3] = fcc1; fj.b[3] = (const float*)d_in[34]; fj.ld[3] = 1024; fj.n0[3] = 0; fj.n1[3] = 1024;
        fj.C[4] = fcc2; fj.b[4] = (const float*)d_in[36]; fj.ld[4] = 512;  fj.n0[4] = 0; fj.n1[4] = 512;
        fj.C[5] = nullptr; fj.b[5] = nullptr; fj.ld[5] = 0; fj.n0[5] = 0; fj.n1[5] = 0;
        prefill6<<<dim3((B * 1024 + 255) / 256, 1, 5), 256, 0, stream>>>(fj, B);
    }

    // ---- protein branch (fully fused; writes xc[:,128:256] incl. bias) ----
    prot_fused<<<B, 256, 0, stream>>>(target, (const float*)d_in[29], (const float*)d_in[28],
                                      (const float*)d_in[30], (const float*)d_in[31],
                                      (const float*)d_in[32], xc);

    // ---- graph FC chain (relu on consumer A-load via klim) ----
    launch_gemm_small(gsum, 624, (const float*)d_in[22], 512, fc1, 512, B, 624, 512, 0, stream);
    launch_gemm_small(fc1, 512, (const float*)d_in[24], 1024, fc2, 1024, B, 512, 1024, 512,
                      stream);
    launch_gemm_small(fc2, 1024, (const float*)d_in[26], 128, xc, 256, B, 1024, 128, 1024,
                      stream);  // xc[:, :128]

    // ---- head (f1 A = xc: relu only graph half, k < 128) ----
    launch_gemm_small(xc, 256, (const float*)d_in[33], 1024, fcc1, 1024, B, 256, 1024, 128,
                      stream);
    launch_gemm_small(fcc1, 1024, (const float*)d_in[35], 512, fcc2, 512, B, 1024, 512, 1024,
                      stream);
    out_kernel<<<(B + 3) / 4, 256, 0, stream>>>(fcc2, (const float*)d_in[37],
                                                (const float*)d_in[38], (float*)d_out, B, 512);
}

// Round 9
// 774.174 us; speedup vs baseline: 1.0964x; 1.0964x over previous
//
#include <hip/hip_runtime.h>
#include <hip/hip_bf16.h>

typedef unsigned short u16;
typedef __attribute__((ext_vector_type(8))) short bh8;     // 8 bf16 (4 VGPRs)
typedef __attribute__((ext_vector_type(4))) float f32x4;   // MFMA acc

static __device__ __forceinline__ float b2fu(u16 u) {
    union { float f; unsigned int i; } x;
    x.i = ((unsigned int)u) << 16;
    return x.f;
}
static __device__ __forceinline__ u16 f2bu(float f) {
    __hip_bfloat16 h = __float2bfloat16(f);  // RNE
    union { __hip_bfloat16 h; u16 u; } x;
    x.h = h;
    return x.u;
}

// async global->LDS, 16B per lane; lds dest must be wave-uniform (HW adds lane*16)
static __device__ __forceinline__ void gload16(const u16* g, u16* l) {
    __builtin_amdgcn_global_load_lds(
        (const __attribute__((address_space(1))) unsigned int*)(const void*)g,
        (__attribute__((address_space(3))) unsigned int*)(void*)l, 16, 0, 0);
}

// ---------------- fallback ----------------

__global__ __launch_bounds__(256) void const_out_kernel(float* __restrict__ out, float v, int n) {
    int i = blockIdx.x * 256 + threadIdx.x;
    if (i < n) out[i] = v;
}

// ---------------- CSR build ----------------

__global__ __launch_bounds__(256) void hist2_kernel(const int* __restrict__ dst,
                                                    const int* __restrict__ batch,
                                                    int* __restrict__ hist,
                                                    int* __restrict__ ghist, int E, int N) {
    int i = blockIdx.x * 256 + threadIdx.x;
    if (i < E) atomicAdd(&hist[dst[i]], 1);
    else if (i < E + N) atomicAdd(&ghist[batch[i - E]], 1);
}

__global__ __launch_bounds__(256) void scan_tiles(const int* __restrict__ hist, int N,
                                                  int* __restrict__ rowptr,
                                                  int* __restrict__ tsum) {
    int tid = threadIdx.x;
    int i = blockIdx.x * 256 + tid;
    int v = (i < N) ? hist[i] : 0;
    __shared__ int s[256];
    s[tid] = v;
    __syncthreads();
    for (int off = 1; off < 256; off <<= 1) {
        int t = (tid >= off) ? s[tid - off] : 0;
        __syncthreads();
        s[tid] += t;
        __syncthreads();
    }
    if (i < N) rowptr[i] = s[tid] - v;
    if (tid == 255) tsum[blockIdx.x] = s[255];
}

// block 0: scan of tile sums (-> toff, total); block 1: graph-offset scan (ghist -> goff)
__global__ __launch_bounds__(256) void scan_misc(const int* __restrict__ tsum, int ntiles,
                                                 int* __restrict__ toff,
                                                 int* __restrict__ totalp,
                                                 const int* __restrict__ ghist,
                                                 int* __restrict__ goff,
                                                 int* __restrict__ gfill, int B) {
    int tid = threadIdx.x;
    if (blockIdx.x == 0) {
        int v = (tid < ntiles) ? tsum[tid] : 0;
        __shared__ int s[256];
        s[tid] = v;
        __syncthreads();
        for (int off = 1; off < 256; off <<= 1) {
            int t = (tid >= off) ? s[tid - off] : 0;
            __syncthreads();
            s[tid] += t;
            __syncthreads();
        }
        if (tid < ntiles) toff[tid] = s[tid] - v;
        if (tid == 255) *totalp = s[255];
    } else {
        int v = (tid < B) ? ghist[tid] : 0;
        __shared__ int s2[256];
        s2[tid] = v;
        __syncthreads();
        for (int off = 1; off < 256; off <<= 1) {
            int t = (tid >= off) ? s2[tid - off] : 0;
            __syncthreads();
            s2[tid] += t;
            __syncthreads();
        }
        if (tid < B) {
            goff[tid] = s2[tid] - v;
            gfill[tid] = s2[tid] - v;
        }
        if (tid == 255) goff[B] = s2[255];
    }
}

__global__ __launch_bounds__(256) void scan_apply(int* __restrict__ rowptr,
                                                  const int* __restrict__ toff, int N,
                                                  int* __restrict__ fill) {
    int i = blockIdx.x * 256 + threadIdx.x;
    if (i < N) {
        int r = rowptr[i] + toff[blockIdx.x];
        rowptr[i] = r;
        fill[i] = r;
    }
}

__global__ __launch_bounds__(256) void scatter_kernel(const int* __restrict__ src,
                                                      const int* __restrict__ dst,
                                                      int* __restrict__ fill,
                                                      int* __restrict__ srcs, int E) {
    int e = blockIdx.x * 256 + threadIdx.x;
    if (e < E) {
        int p = atomicAdd(&fill[dst[e]], 1);
        srcs[p] = src[e];
    }
}

// ---------------- GENConv aggregation -> bf16 A-operand (K-padded), VEC feats/thread ------

template <typename T, int VEC>
__global__ __launch_bounds__(256) void agg_kernel(const T* __restrict__ x,
                                                  const int* __restrict__ rowptr,
                                                  const int* __restrict__ srcs,
                                                  u16* __restrict__ out, int d, int ldx,
                                                  int Kp, int N) {
    int n = blockIdx.y * 4 + (threadIdx.x >> 6);
    int f0 = (blockIdx.x * 64 + (threadIdx.x & 63)) * VEC;
    if (n >= N || f0 >= Kp) return;
    size_t o = (size_t)n * Kp + f0;
    if (f0 >= d) {
#pragma unroll
        for (int i = 0; i < VEC; i++) out[o + i] = 0;
        return;
    }
    auto loadV = [&](const T* row, float* v) {
        if constexpr (sizeof(T) == 4) {
            float2 t = *reinterpret_cast<const float2*>(row);
            v[0] = t.x; v[1] = t.y;
        } else if constexpr (VEC == 2) {
            unsigned int u = *reinterpret_cast<const unsigned int*>(row);
            v[0] = b2fu((u16)(u & 0xffff)); v[1] = b2fu((u16)(u >> 16));
        } else if constexpr (VEC == 4) {
            uint2 u = *reinterpret_cast<const uint2*>(row);
            v[0] = b2fu((u16)(u.x & 0xffff)); v[1] = b2fu((u16)(u.x >> 16));
            v[2] = b2fu((u16)(u.y & 0xffff)); v[3] = b2fu((u16)(u.y >> 16));
        } else {
            uint4 u = *reinterpret_cast<const uint4*>(row);
            v[0] = b2fu((u16)(u.x & 0xffff)); v[1] = b2fu((u16)(u.x >> 16));
            v[2] = b2fu((u16)(u.y & 0xffff)); v[3] = b2fu((u16)(u.y >> 16));
            v[4] = b2fu((u16)(u.z & 0xffff)); v[5] = b2fu((u16)(u.z >> 16));
            v[6] = b2fu((u16)(u.w & 0xffff)); v[7] = b2fu((u16)(u.w >> 16));
        }
    };
    int e0 = rowptr[n], e1 = rowptr[n + 1];
    float s[VEC] = {}, t[VEC] = {};
    for (int e = e0; e < e1; e++) {
        int sr = srcs[e];
        float v[VEC];
        loadV(x + (size_t)sr * ldx + f0, v);
#pragma unroll
        for (int i = 0; i < VEC; i++) {
            float m = fmaxf(v[i], 0.f) + 1e-7f;
            float wv = __expf(m);
            s[i] += wv;
            t[i] += m * wv;
        }
    }
    float xs[VEC];
    loadV(x + (size_t)n * ldx + f0, xs);
    u16 ob[VEC];
#pragma unroll
    for (int i = 0; i < VEC; i++) {
        float a = t[i] / (s[i] + 1e-16f) + xs[i];
        ob[i] = (f0 + i < d) ? f2bu(a) : (u16)0;
    }
    if constexpr (VEC == 2) {
        *reinterpret_cast<unsigned int*>(out + o) =
            (unsigned int)ob[0] | ((unsigned int)ob[1] << 16);
    } else if constexpr (VEC == 4) {
        uint2 u;
        u.x = (unsigned int)ob[0] | ((unsigned int)ob[1] << 16);
        u.y = (unsigned int)ob[2] | ((unsigned int)ob[3] << 16);
        *reinterpret_cast<uint2*>(out + o) = u;
    } else {
        uint4 u;
        u.x = (unsigned int)ob[0] | ((unsigned int)ob[1] << 16);
        u.y = (unsigned int)ob[2] | ((unsigned int)ob[3] << 16);
        u.z = (unsigned int)ob[4] | ((unsigned int)ob[5] << 16);
        u.w = (unsigned int)ob[6] | ((unsigned int)ob[7] << 16);
        *reinterpret_cast<uint4*>(out + o) = u;
    }
}

// ---------------- batched weight transpose+cvt: W[K,N] f32 -> WT[Np,Kp] bf16 ----------------

struct WtJobs {
    const float* W[6];
    u16* WT[6];
    int K[6], N[6], Kp[6], Np[6];
};

__global__ __launch_bounds__(256) void wt_cvt6(WtJobs jb) {
    int jz = blockIdx.z;
    int Kp = jb.Kp[jz], Np = jb.Np[jz];
    int n = blockIdx.y * 4 + (threadIdx.x >> 6);
    int k = blockIdx.x * 64 + (threadIdx.x & 63);
    if (n >= Np || k >= Kp) return;
    int K = jb.K[jz], N = jb.N[jz];
    float v = (n < N && k < K) ? jb.W[jz][(size_t)k * N + n] : 0.f;
    jb.WT[jz][(size_t)n * Kp + k] = f2bu(v);
}

// ---------------- MFMA GEMM, fused variants ----------------
// Base: XCD swizzle, BK=32, 2 LDS buffers, minimal 2-phase. Column 16B-slots
// XOR-swizzled by ((row>>1)&3) on both sides.
// AMODE 0: A staged via global_load_lds.
// AMODE 1: A reg-staged with BN(scale/shift)+relu applied in-flight; scale/shift
//          COMPUTED IN-KERNEL from sum/sumsq/gamma/beta into LDS (replaces bn_final).
// EMODE 0: plain epilogue (bias [+relu]); zero-fills pad cols Ncols<=n<ldc.
// EMODE 1: BN-stats epilogue: K-padded C + per-column sum/sumsq atomics.
// EMODE 2: split-K atomicAdd epilogue (no bias; C float, zero-initialized). K-slice
//          selected by blockIdx.y: koff = blockIdx.y * kLen.

template <int AMODE, int EMODE, bool RELU, typename CT>
__global__ __launch_bounds__(256) void gemm_mfma(const u16* __restrict__ A,
                                                 const u16* __restrict__ BT,
                                                 const float* __restrict__ bias,
                                                 CT* __restrict__ C, int ldc, int M, int Ncols,
                                                 int Kp, int kLen, int nbx, int nby, int spx,
                                                 const float* __restrict__ bnsum,
                                                 const float* __restrict__ bnsumsq,
                                                 const float* __restrict__ gamma,
                                                 const float* __restrict__ beta,
                                                 float invN, int dhBN,
                                                 float* __restrict__ osum,
                                                 float* __restrict__ osumsq) {
    int xcd = blockIdx.x & 7;
    int j = blockIdx.x >> 3;
    int bx = j % nbx;
    int by = xcd * spx + j / nbx;
    if (by >= nby) return;
    __shared__ u16 As[2][128 * 32];
    __shared__ u16 Bs[2][128 * 32];
    __shared__ float scl[AMODE == 1 ? 640 : 1];
    __shared__ float shf[AMODE == 1 ? 640 : 1];
    const int tid = threadIdx.x;
    const int lane = tid & 63;
    const int w = tid >> 6;
    const int bm = by * 128;
    const int bn = bx * 128;
    const int kw = blockIdx.y * kLen;  // K-slice base (split-K); 0 otherwise
    f32x4 acc[4][4] = {};

    if constexpr (AMODE == 1) {  // in-kernel bn_final (redundant per block, trivial)
        for (int i = tid; i < Kp; i += 256) {
            float sc = 0.f, sh = 0.f;
            if (i < dhBN) {
                float mu = bnsum[i] * invN;
                float var = bnsumsq[i] * invN - mu * mu;
                sc = gamma[i] / sqrtf(var + 1e-5f);
                sh = beta[i] - mu * sc;
            }
            scl[i] = sc;
            shf[i] = sh;
        }
        __syncthreads();
    }

    const int r0 = w * 16 + (lane >> 2);
    const int r1 = r0 + 64;                       // sigma(r1) == sigma(r0)
    const int sw = ((lane & 3) ^ ((r0 >> 1) & 3)) << 3;  // u16 offset of source col
    const u16* Ag0 = A + (size_t)(bm + r0) * Kp + sw + kw;
    const u16* Ag1 = A + (size_t)(bm + r1) * Kp + sw + kw;
    const u16* Bg0 = BT + (size_t)(bn + r0) * Kp + sw + kw;
    const u16* Bg1 = BT + (size_t)(bn + r1) * Kp + sw + kw;
    const int wb = w << 9;  // wave LDS base (u16 units): w*1024B

    uint4 a0r, a1r;  // AMODE1 in-flight A regs
    auto stageB = [&](int b, int koff) {
        gload16(Bg0 + koff, &Bs[b][wb]);
        gload16(Bg1 + koff, &Bs[b][2048 + wb]);
    };
    auto stageA_lds = [&](int b, int koff) {
        gload16(Ag0 + koff, &As[b][wb]);
        gload16(Ag1 + koff, &As[b][2048 + wb]);
    };
    auto loadA_reg = [&](int koff) {
        a0r = *reinterpret_cast<const uint4*>(Ag0 + koff);
        a1r = *reinterpret_cast<const uint4*>(Ag1 + koff);
    };
    auto writeA_reg = [&](int b, int koff) {
        int f0 = sw + kw + koff;  // feature (=source col) index of this lane's 8 elems
        float4 sc0 = *reinterpret_cast<const float4*>(&scl[f0]);
        float4 sc1 = *reinterpret_cast<const float4*>(&scl[f0 + 4]);
        float4 sh0 = *reinterpret_cast<const float4*>(&shf[f0]);
        float4 sh1 = *reinterpret_cast<const float4*>(&shf[f0 + 4]);
        auto tf2 = [](unsigned int u, float sa, float sb, float ha, float hb) {
            float h0 = b2fu((u16)(u & 0xffff)), h1 = b2fu((u16)(u >> 16));
            float v0 = fmaxf(fmaf(h0, sa, ha), 0.f);
            float v1 = fmaxf(fmaf(h1, sb, hb), 0.f);
            return (unsigned int)f2bu(v0) | ((unsigned int)f2bu(v1) << 16);
        };
        uint4 o0, o1;
        o0.x = tf2(a0r.x, sc0.x, sc0.y, sh0.x, sh0.y);
        o0.y = tf2(a0r.y, sc0.z, sc0.w, sh0.z, sh0.w);
        o0.z = tf2(a0r.z, sc1.x, sc1.y, sh1.x, sh1.y);
        o0.w = tf2(a0r.w, sc1.z, sc1.w, sh1.z, sh1.w);
        o1.x = tf2(a1r.x, sc0.x, sc0.y, sh0.x, sh0.y);
        o1.y = tf2(a1r.y, sc0.z, sc0.w, sh0.z, sh0.w);
        o1.z = tf2(a1r.z, sc1.x, sc1.y, sh1.x, sh1.y);
        o1.w = tf2(a1r.w, sc1.z, sc1.w, sh1.z, sh1.w);
        *reinterpret_cast<uint4*>(&As[b][wb + lane * 8]) = o0;
        *reinterpret_cast<uint4*>(&As[b][2048 + wb + lane * 8]) = o1;
    };

    // fragment read geometry (XOR involution cancels against the staged layout)
    const int fm = (w >> 1) * 64 + (lane & 15);
    const int fn = (w & 1) * 64 + (lane & 15);
    const int g = lane >> 4;
    const int ka = (g ^ ((fm >> 1) & 3)) << 3;  // sigma(fm+mt*16)==sigma(fm)
    const int kb = (g ^ ((fn >> 1) & 3)) << 3;

    const int nk = kLen >> 5;
    // prologue: stage tile 0, drain, barrier
    if constexpr (AMODE == 0) {
        stageA_lds(0, 0);
        stageB(0, 0);
        asm volatile("s_waitcnt vmcnt(0)" ::: "memory");
    } else {
        loadA_reg(0);
        stageB(0, 0);
        asm volatile("s_waitcnt vmcnt(0)" ::: "memory");
        writeA_reg(0, 0);
        asm volatile("s_waitcnt lgkmcnt(0)" ::: "memory");
    }
    __builtin_amdgcn_s_barrier();
    for (int k = 0; k < nk; k++) {
        const int cur = k & 1;
        if (k + 1 < nk) {  // prefetch next tile
            if constexpr (AMODE == 0) stageA_lds(cur ^ 1, (k + 1) << 5);
            else loadA_reg((k + 1) << 5);
            stageB(cur ^ 1, (k + 1) << 5);
        }
        bh8 af[4], bf[4];
#pragma unroll
        for (int mt = 0; mt < 4; mt++)
            af[mt] = *reinterpret_cast<const bh8*>(&As[cur][(fm + mt * 16) * 32 + ka]);
#pragma unroll
        for (int nt = 0; nt < 4; nt++)
            bf[nt] = *reinterpret_cast<const bh8*>(&Bs[cur][(fn + nt * 16) * 32 + kb]);
        asm volatile("s_waitcnt lgkmcnt(0)" ::: "memory");
        __builtin_amdgcn_sched_barrier(0);  // rule #18: don't hoist MFMA above the wait
        __builtin_amdgcn_s_setprio(1);
#pragma unroll
        for (int mt = 0; mt < 4; mt++)
#pragma unroll
            for (int nt = 0; nt < 4; nt++)
                acc[mt][nt] = __builtin_amdgcn_mfma_f32_16x16x32_bf16(af[mt], bf[nt],
                                                                      acc[mt][nt], 0, 0, 0);
        __builtin_amdgcn_s_setprio(0);
        __builtin_amdgcn_sched_barrier(0);  // keep MFMAs above the drain
        asm volatile("s_waitcnt vmcnt(0)" ::: "memory");  // next tile's loads landed
        if constexpr (AMODE == 1) {
            __builtin_amdgcn_sched_barrier(0);
            if (k + 1 < nk) writeA_reg(cur ^ 1, (k + 1) << 5);
            asm volatile("s_waitcnt lgkmcnt(0)" ::: "memory");  // ds_writes visible
        }
        __builtin_amdgcn_s_barrier();  // all waves: reads of cur done, nxt ready
    }
    const int rq = (lane >> 4) * 4;
    const int cl = lane & 15;
    if constexpr (EMODE == 0) {
#pragma unroll
        for (int mt = 0; mt < 4; mt++) {
#pragma unroll
            for (int nt = 0; nt < 4; nt++) {
                int n = bn + (w & 1) * 64 + nt * 16 + cl;
                if (n >= ldc) continue;
                bool valid = (n < Ncols);
                float bv = valid ? bias[n] : 0.f;
#pragma unroll
                for (int r = 0; r < 4; r++) {
                    int m = bm + (w >> 1) * 64 + mt * 16 + rq + r;
                    if (m >= M) continue;
                    float v = valid ? acc[mt][nt][r] + bv : 0.f;
                    if (RELU) v = fmaxf(v, 0.f);
                    if (sizeof(CT) == 2)
                        C[(size_t)m * ldc + n] = (CT)f2bu(v);
                    else
                        C[(size_t)m * ldc + n] = (CT)v;
                }
            }
        }
    } else if constexpr (EMODE == 1) {
        // BN-stats epilogue
        float cs[4] = {0.f, 0.f, 0.f, 0.f}, cq[4] = {0.f, 0.f, 0.f, 0.f};
#pragma unroll
        for (int nt = 0; nt < 4; nt++) {
            int n = bn + (w & 1) * 64 + nt * 16 + cl;
            if (n >= ldc) continue;
            float bv = (n < Ncols) ? bias[n] : 0.f;
#pragma unroll
            for (int mt = 0; mt < 4; mt++) {
#pragma unroll
                for (int r = 0; r < 4; r++) {
                    int m = bm + (w >> 1) * 64 + mt * 16 + rq + r;
                    if (m >= M) continue;
                    float v = (n < Ncols) ? acc[mt][nt][r] + bv : 0.f;
                    C[(size_t)m * ldc + n] = (CT)f2bu(v);
                    cs[nt] += v;
                    cq[nt] += v * v;
                }
            }
        }
        float* red = (float*)&As[0][0];  // 128 cols x 8 slots x {sum,sq} = 8 KB
        const int slot = (w >> 1) * 4 + (lane >> 4);
#pragma unroll
        for (int nt = 0; nt < 4; nt++) {
            int nl = (w & 1) * 64 + nt * 16 + cl;
            red[nl * 8 + slot] = cs[nt];
            red[1024 + nl * 8 + slot] = cq[nt];
        }
        __syncthreads();
        if (tid < 128) {
            int n = bn + tid;
            if (n < Ncols) {
                float s = 0.f, q = 0.f;
#pragma unroll
                for (int i = 0; i < 8; i++) {
                    s += red[tid * 8 + i];
                    q += red[1024 + tid * 8 + i];
                }
                atomicAdd(&osum[n], s);
                atomicAdd(&osumsq[n], q);
            }
        }
    } else {
        // split-K: atomic accumulate into zero-initialized float C (no bias)
#pragma unroll
        for (int mt = 0; mt < 4; mt++) {
#pragma unroll
            for (int nt = 0; nt < 4; nt++) {
                int n = bn + (w & 1) * 64 + nt * 16 + cl;
                if (n >= Ncols) continue;
#pragma unroll
                for (int r = 0; r < 4; r++) {
                    int m = bm + (w >> 1) * 64 + mt * 16 + rq + r;
                    if (m >= M) continue;
                    atomicAdd((float*)&C[(size_t)m * ldc + n], acc[mt][nt][r]);
                }
            }
        }
    }
}

// ---------------- segmented global mean pool (batch sorted) ----------------

__global__ __launch_bounds__(256) void pool_seg(const u16* __restrict__ h,
                                                const int* __restrict__ goff,
                                                float* __restrict__ gsum, int d) {
    int g = blockIdx.y;
    int c = threadIdx.x & 63;
    int f = blockIdx.x * 64 + c;
    int wv = threadIdx.x >> 6;
    int r0 = goff[g], r1 = goff[g + 1];
    float s = 0.f;
    if (f < d)
        for (int r = r0 + wv; r < r1; r += 4) s += b2fu(h[(size_t)r * d + f]);
    __shared__ float ls[4][64];
    ls[wv][c] = s;
    __syncthreads();
    if (wv == 0 && f < d) {
        float tot = ls[0][c] + ls[1][c] + ls[2][c] + ls[3][c];
        gsum[(size_t)g * d + f] = tot / fmaxf((float)(r1 - r0), 1.f);
    }
}

// ---------------- split-K GEMM for small-M FC chain (f32) ----------------
// C pre-filled with bias; relu applied to A elements with k < klim.

__global__ __launch_bounds__(256) void gemm_sk(const float* __restrict__ A, int lda,
                                               const float* __restrict__ B, int ldb,
                                               float* __restrict__ C, int ldc, int M, int K,
                                               int Nn, int KC, int klim) {
    __shared__ float As[16][17];
    __shared__ float Bs[16][68];
    const int tid = threadIdx.x;
    const int bn = blockIdx.x * 64;
    const int bm = blockIdx.y * 16;
    const int k0 = blockIdx.z * KC;
    const int kend = min(K, k0 + KC);
    const int tx = tid & 63;
    const int ty = tid >> 6;
    float acc[4] = {};
    const int am = bm + (tid >> 4);
    const int ak = tid & 15;
    for (int kk0 = k0; kk0 < kend; kk0 += 16) {
        {
            int k = kk0 + ak;
            float v = (am < M && k < kend) ? A[(size_t)am * lda + k] : 0.f;
            if (k < klim) v = fmaxf(v, 0.f);
            As[ak][tid >> 4] = v;
        }
#pragma unroll
        for (int i = 0; i < 4; i++) {
            int k = kk0 + ty + 4 * i;
            Bs[ty + 4 * i][tx] = (k < kend && bn + tx < Nn) ? B[(size_t)k * ldb + bn + tx] : 0.f;
        }
        __syncthreads();
#pragma unroll
        for (int kk = 0; kk < 16; kk++) {
            float b = Bs[kk][tx];
#pragma unroll
            for (int i = 0; i < 4; i++) acc[i] = fmaf(As[kk][ty + 4 * i], b, acc[i]);
        }
        __syncthreads();
    }
    if (bn + tx < Nn) {
#pragma unroll
        for (int i = 0; i < 4; i++) {
            int m = bm + ty + 4 * i;
            if (m < M) atomicAdd(&C[(size_t)m * ldc + bn + tx], acc[i]);
        }
    }
}

static void launch_gemm_small(const float* A, int lda, const float* B, int ldb,
                              float* C, int ldc, int M, int K, int Nn, int klim,
                              hipStream_t stream) {
    int gx = (Nn + 63) / 64, gy = (M + 15) / 16;
    int tiles = gx * gy;
    int ksplit = 512 / tiles;
    if (ksplit < 1) ksplit = 1;
    int maxsplit = (K + 63) / 64;
    if (ksplit > maxsplit) ksplit = maxsplit;
    int KC = (((K + ksplit - 1) / ksplit) + 15) & ~15;
    ksplit = (K + KC - 1) / KC;
    gemm_sk<<<dim3(gx, gy, ksplit), 256, 0, stream>>>(A, lda, B, ldb, C, ldc, M, K, Nn, KC,
                                                      klim);
}

// ---------------- batched bias prefill for FC output buffers ----------------

struct FillJobs {
    float* C[6];
    const float* b[6];
    int ld[6], n0[6], n1[6];
};

__global__ __launch_bounds__(256) void prefill6(FillJobs jb, int M) {
    int jz = blockIdx.z;
    int w = jb.n1[jz] - jb.n0[jz];
    int i = blockIdx.x * 256 + threadIdx.x;
    if (i >= M * w) return;
    int m = i / w, n = i - m * w;
    jb.C[jz][(size_t)m * jb.ld[jz] + jb.n0[jz] + n] = jb.b[jz][n];
}

// ---------------- protein branch as GEMM (round-6 structure, measured fast) ----------------
// S[(b*26+t), (o*8+k)] = sum_i [target[b,i]==t] * cw[o,i,k]  ==  H @ cwT

__global__ __launch_bounds__(256) void hone_kernel(const int* __restrict__ target,
                                                   u16* __restrict__ H, int total) {
    int i = blockIdx.x * 256 + threadIdx.x;
    if (i >= total) return;
    int b = i / 1000, pos = i - b * 1000;
    int t = target[i];
    H[((size_t)b * 26 + t) * 1024 + pos] = 0x3F80;  // bf16(1.0)
}

__global__ __launch_bounds__(256) void cwt_cvt(const float* __restrict__ cw,
                                               u16* __restrict__ BT) {
    int n = blockIdx.y;                           // 256
    int kk = blockIdx.x * 256 + threadIdx.x;      // 1024
    int o = n >> 3, k = n & 7;
    float v = (kk < 1000) ? cw[(size_t)o * 8000 + (size_t)kk * 8 + k] : 0.f;
    BT[(size_t)n * 1024 + kk] = f2bu(v);
}

// conv[b,o,w] = cb[o] + sum_t sum_k S[b*6656 + t*256 + o*8+k] * emb[t*128 + w+k]
__global__ __launch_bounds__(256) void prot_conv_kernel(const float* __restrict__ S,
                                                        const float* __restrict__ emb,
                                                        const float* __restrict__ cb,
                                                        float* __restrict__ out) {
    int b = blockIdx.x;
    int tid = threadIdx.x;
    __shared__ float Sl[6656];
    __shared__ float el[26 * 128];
    for (int i = tid; i < 6656; i += 256) Sl[i] = S[(size_t)b * 6656 + i];
    for (int i = tid; i < 26 * 128; i += 256) el[i] = emb[i];
    __syncthreads();
    for (int j = tid; j < 3872; j += 256) {
        int o = j / 121;
        int w = j - o * 121;
        float acc = cb[o];
        for (int t = 0; t < 26; t++) {
#pragma unroll
            for (int k = 0; k < 8; k++)
                acc = fmaf(Sl[t * 256 + o * 8 + k], el[t * 128 + w + k], acc);
        }
        out[(size_t)b * 3872 + j] = acc;
    }
}

// ---------------- final matvec (relu on A load) ----------------

__global__ __launch_bounds__(256) void out_kernel(const float* __restrict__ A,
                                                  const float* __restrict__ w,
                                                  const float* __restrict__ bias,
                                                  float* __restrict__ out, int M, int K) {
    int wave = threadIdx.x >> 6;
    int lane = threadIdx.x & 63;
    int r = blockIdx.x * 4 + wave;
    if (r >= M) return;
    float acc = 0.f;
    for (int k = lane; k < K; k += 64) acc += fmaxf(A[(size_t)r * K + k], 0.f) * w[k];
    for (int off = 32; off > 0; off >>= 1) acc += __shfl_down(acc, off, 64);
    if (lane == 0) out[r] = acc + bias[0];
}

// ---------------- host orchestration ----------------

static inline int KP(int k) { return (k + 31) & ~31; }
static inline int NP(int n) { return (n + 127) & ~127; }
static inline int LD8(int n) { return (n + 7) & ~7; }

extern "C" void kernel_launch(void* const* d_in, const int* in_sizes, int n_in, void* d_out,
                              int out_size, void* d_ws, size_t ws_size, hipStream_t stream) {
    static const int exp_sizes[39] = {
        2340000, 300000, 30000, 256000,
        12168, 156, 156, 156, 12168, 78,
        12168, 156, 156, 156, 48672, 312,
        194688, 624, 624, 624, 389376, 624,
        319488, 512, 524288, 1024, 131072, 128,
        3328, 256000, 32, 495616, 128,
        262144, 1024, 524288, 512, 512, 1};
    int bad = (n_in != 39) ? 100 : -1;
    if (bad < 0)
        for (int i = 0; i < 39; i++)
            if (in_sizes[i] != exp_sizes[i]) { bad = i; break; }
    if (bad >= 0) {
        const_out_kernel<<<1, 256, 0, stream>>>((float*)d_out, 2048.f + 8.f * bad, out_size);
        return;
    }

    const int N = 30000, E = 150000, B = 256;
    const int Mp = 30080;   // 235*128
    const int nby = 235, spx = 30;
    const int ntiles = (N + 255) / 256;  // 118
    const float* x_in = (const float*)d_in[0];
    const int* ei = (const int*)d_in[1];
    const int* src = ei;
    const int* dst = ei + E;
    const int* batch = (const int*)d_in[2];
    const int* target = (const int*)d_in[3];

    char* p = (char*)d_ws;
    auto carve = [&](size_t bytes) {
        char* r = p;
        p += (bytes + 15) & ~(size_t)15;
        return r;
    };
    // hist + ghist + per-layer BN sums: one contiguous zero region
    int* hist = (int*)carve((size_t)(N + B) * 4 + 3 * 1280 * 4);
    int* ghist = hist + N;
    float* sums = (float*)(hist + N + B);  // 3 layers x {sum[640], sumsq[640]}
    const size_t zero_bytes = (size_t)(N + B) * 4 + 3 * 1280 * 4;
    int* rowptr = (int*)carve((size_t)(N + 1) * 4);
    int* fill = (int*)carve((size_t)N * 4);
    int* srcs = (int*)carve((size_t)E * 4);
    int* goff = (int*)carve((size_t)(B + 1) * 4);
    int* gfill = (int*)carve((size_t)B * 4);
    int* tsum = (int*)carve(256 * 4);
    int* toff = (int*)carve(256 * 4);
    float* gsum = (float*)carve((size_t)B * 624 * 4);
    float* fc1 = (float*)carve((size_t)B * 512 * 4);
    float* fc2 = (float*)carve((size_t)B * 1024 * 4);
    float* xc = (float*)carve((size_t)B * 256 * 4);
    float* fcc1 = (float*)carve((size_t)B * 1024 * 4);
    float* fcc2 = (float*)carve((size_t)B * 512 * 4);
    float* Sbuf = (float*)carve((size_t)B * 6656 * 4);
    float* convb = (float*)carve((size_t)B * 3872 * 4);
    u16* Hbuf = (u16*)carve((size_t)B * 26 * 1024 * 2);  // one-hot, 13.6 MB
    u16* cwT = (u16*)carve((size_t)256 * 1024 * 2);
    u16* Abf = (u16*)carve((size_t)Mp * 640 * 2);
    u16* hmidb = (u16*)carve((size_t)Mp * 640 * 2);   // K-padded h (GEMM2 A operand)
    u16* Lout = (u16*)carve((size_t)N * 624 * 2);
    struct Layer { int di, dh, dn, w1, b1, g, be, w2, b2; };
    const Layer L[3] = {
        {78, 156, 78, 4, 5, 6, 7, 8, 9},
        {78, 156, 312, 10, 11, 12, 13, 14, 15},
        {312, 624, 624, 16, 17, 18, 19, 20, 21},
    };
    u16* WT1[3];
    u16* WT2[3];
    for (int li = 0; li < 3; li++) {
        WT1[li] = (u16*)carve((size_t)NP(L[li].dh) * KP(L[li].di) * 2);
        WT2[li] = (u16*)carve((size_t)NP(L[li].dn) * KP(L[li].dh) * 2);
    }
    size_t need = (size_t)(p - (char*)d_ws);
    if (ws_size < need) {
        const_out_kernel<<<1, 256, 0, stream>>>((float*)d_out,
                                                1024.f + (float)(ws_size >> 20), out_size);
        return;
    }

    // ---- CSR by dst (hierarchical scan) + graph offsets ----
    hipMemsetAsync(hist, 0, zero_bytes, stream);
    hist2_kernel<<<(E + N + 255) / 256, 256, 0, stream>>>(dst, batch, hist, ghist, E, N);
    scan_tiles<<<ntiles, 256, 0, stream>>>(hist, N, rowptr, tsum);
    scan_misc<<<2, 256, 0, stream>>>(tsum, ntiles, toff, rowptr + N, ghist, goff, gfill, B);
    scan_apply<<<ntiles, 256, 0, stream>>>(rowptr, toff, N, fill);
    scatter_kernel<<<(E + 255) / 256, 256, 0, stream>>>(src, dst, fill, srcs, E);

    // ---- weight transpose+cvt (single batched dispatch) ----
    {
        WtJobs jb;
        int mgx = 1, mgy = 1;
        for (int li = 0; li < 3; li++) {
            jb.W[2 * li] = (const float*)d_in[L[li].w1];
            jb.WT[2 * li] = WT1[li];
            jb.K[2 * li] = L[li].di; jb.N[2 * li] = L[li].dh;
            jb.Kp[2 * li] = KP(L[li].di); jb.Np[2 * li] = NP(L[li].dh);
            jb.W[2 * li + 1] = (const float*)d_in[L[li].w2];
            jb.WT[2 * li + 1] = WT2[li];
            jb.K[2 * li + 1] = L[li].dh; jb.N[2 * li + 1] = L[li].dn;
            jb.Kp[2 * li + 1] = KP(L[li].dh); jb.Np[2 * li + 1] = NP(L[li].dn);
        }
        for (int i = 0; i < 6; i++) {
            int gx = (jb.Kp[i] + 63) / 64, gy = jb.Np[i] / 4;
            if (gx > mgx) mgx = gx;
            if (gy > mgy) mgy = gy;
        }
        wt_cvt6<<<dim3(mgx, mgy, 6), 256, 0, stream>>>(jb);
    }

    // ---- GENConv layers (BN stats fused into GEMM1, bn_final+BN apply fused into GEMM2) --
    const int ldo[3] = {LD8(L[0].dn), LD8(L[1].dn), LD8(L[2].dn)};  // 80, 312, 624
    for (int li = 0; li < 3; li++) {
        const int di = L[li].di, dh = L[li].dh, dn = L[li].dn;
        const int Kp1 = KP(di), Kp2 = KP(dh);
        float* sumL = sums + li * 1280;
        float* sumsqL = sumL + 640;
        if (li == 0)
            agg_kernel<float, 2><<<dim3((Kp1 / 2 + 63) / 64, (N + 3) / 4), 256, 0, stream>>>(
                x_in, rowptr, srcs, Abf, di, di, Kp1, N);
        else if (li == 1)
            agg_kernel<u16, 4><<<dim3((Kp1 / 4 + 63) / 64, (N + 3) / 4), 256, 0, stream>>>(
                Lout, rowptr, srcs, Abf, di, ldo[0], Kp1, N);
        else
            agg_kernel<u16, 8><<<dim3((Kp1 / 8 + 63) / 64, (N + 3) / 4), 256, 0, stream>>>(
                Lout, rowptr, srcs, Abf, di, ldo[1], Kp1, N);
        {
            // h = Abf @ W1 + b1 -> hmidb (ldc = Kp2, zero-padded cols) + column stats
            int nbx = NP(dh) / 128;
            gemm_mfma<0, 1, false, u16><<<dim3(8 * spx * nbx), 256, 0, stream>>>(
                Abf, WT1[li], (const float*)d_in[L[li].b1], hmidb, Kp2, N, dh, Kp1, Kp1, nbx,
                nby, spx, nullptr, nullptr, nullptr, nullptr, 0.f, 0, sumL, sumsqL);
        }
        {
            // Lout = relu(bn(h)) @ W2 + b2; scale/shift computed in-kernel from stats
            int nbx = NP(dn) / 128;
            gemm_mfma<1, 0, true, u16><<<dim3(8 * spx * nbx), 256, 0, stream>>>(
                hmidb, WT2[li], (const float*)d_in[L[li].b2], Lout, ldo[li], N, dn, Kp2, Kp2,
                nbx, nby, spx, sumL, sumsqL, (const float*)d_in[L[li].g],
                (const float*)d_in[L[li].be], 1.0f / N, dh, nullptr, nullptr);
        }
    }

    // ---- segmented global mean pool (Lout stride 624 == d) ----
    pool_seg<<<dim3(10, B), 256, 0, stream>>>(Lout, goff, gsum, 624);

    // ---- FC output buffers: prefill with bias ----
    {
        FillJobs fj;
        fj.C[0] = fc1;  fj.b[0] = (const float*)d_in[23]; fj.ld[0] = 512;  fj.n0[0] = 0;   fj.n1[0] = 512;
        fj.C[1] = fc2;  fj.b[1] = (const float*)d_in[25]; fj.ld[1] = 1024; fj.n0[1] = 0;   fj.n1[1] = 1024;
        fj.C[2] = xc;   fj.b[2] = (const float*)d_in[27]; fj.ld[2] = 256;  fj.n0[2] = 0;   fj.n1[2] = 128;
        fj.C[3] = xc;   fj.b[3] = (const float*)d_in[32]; fj.ld[3] = 256;  fj.n0[3] = 128; fj.n1[3] = 256;
        fj.C[4] = fcc1; fj.b[4] = (const float*)d_in[34]; fj.ld[4] = 1024; fj.n0[4] = 0;   fj.n1[4] = 1024;
        fj.C[5] = fcc2; fj.b[5] = (const float*)d_in[36]; fj.ld[5] = 512;  fj.n0[5] = 0;   fj.n1[5] = 512;
        prefill6<<<dim3((B * 1024 + 255) / 256, 1, 6), 256, 0, stream>>>(fj, B);
    }

    // ---- protein branch: S = H @ cwT via split-K MFMA, then conv (round-6 path) ----
    hipMemsetAsync(Hbuf, 0, (size_t)B * 26 * 1024 * 2, stream);
    hipMemsetAsync(Sbuf, 0, (size_t)B * 6656 * 4, stream);
    hone_kernel<<<(B * 1000 + 255) / 256, 256, 0, stream>>>(target, Hbuf, B * 1000);
    cwt_cvt<<<dim3(4, 256), 256, 0, stream>>>((const float*)d_in[29], cwT);
    {
        // M = B*26 = 6656 = 52*128, N = 256, Kp = 1024, split-K x4 (kLen=256, nk=8)
        int nbxS = 2, nbyS = 52, spxS = 7;
        gemm_mfma<0, 2, false, float><<<dim3(8 * spxS * nbxS, 4), 256, 0, stream>>>(
            Hbuf, cwT, nullptr, Sbuf, 256, 6656, 256, 1024, 256, nbxS, nbyS, spxS, nullptr,
            nullptr, nullptr, nullptr, 0.f, 0, nullptr, nullptr);
    }
    prot_conv_kernel<<<B, 256, 0, stream>>>(Sbuf, (const float*)d_in[28],
                                            (const float*)d_in[30], convb);
    launch_gemm_small(convb, 3872, (const float*)d_in[31], 128, xc + 128, 256, B, 3872, 128, 0,
                      stream);  // xc[:, 128:]

    // ---- graph FC chain (relu on consumer A-load via klim) ----
    launch_gemm_small(gsum, 624, (const float*)d_in[22], 512, fc1, 512, B, 624, 512, 0, stream);
    launch_gemm_small(fc1, 512, (const float*)d_in[24], 1024, fc2, 1024, B, 512, 1024, 512,
                      stream);
    launch_gemm_small(fc2, 1024, (const float*)d_in[26], 128, xc, 256, B, 1024, 128, 1024,
                      stream);  // xc[:, :128]

    // ---- head (f1 A = xc: relu only graph half, k < 128) ----
    launch_gemm_small(xc, 256, (const float*)d_in[33], 1024, fcc1, 1024, B, 256, 1024, 128,
                      stream);
    launch_gemm_small(fcc1, 1024, (const float*)d_in[35], 512, fcc2, 512, B, 1024, 512, 1024,
                      stream);
    out_kernel<<<(B + 3) / 4, 256, 0, stream>>>(fcc2, (const float*)d_in[37],
                                                (const float*)d_in[38], (float*)d_out, B, 512);
}

// Round 10
// 746.747 us; speedup vs baseline: 1.1367x; 1.0367x over previous
//
#include <hip/hip_runtime.h>
#include <hip/hip_bf16.h>

typedef unsigned short u16;
typedef __attribute__((ext_vector_type(8))) short bh8;     // 8 bf16 (4 VGPRs)
typedef __attribute__((ext_vector_type(4))) float f32x4;   // MFMA acc

static __device__ __forceinline__ float b2fu(u16 u) {
    union { float f; unsigned int i; } x;
    x.i = ((unsigned int)u) << 16;
    return x.f;
}
static __device__ __forceinline__ u16 f2bu(float f) {
    __hip_bfloat16 h = __float2bfloat16(f);  // RNE
    union { __hip_bfloat16 h; u16 u; } x;
    x.h = h;
    return x.u;
}

// async global->LDS, 16B per lane; lds dest must be wave-uniform (HW adds lane*16)
static __device__ __forceinline__ void gload16(const u16* g, u16* l) {
    __builtin_amdgcn_global_load_lds(
        (const __attribute__((address_space(1))) unsigned int*)(const void*)g,
        (__attribute__((address_space(3))) unsigned int*)(void*)l, 16, 0, 0);
}

// ---------------- fallback ----------------

__global__ __launch_bounds__(256) void const_out_kernel(float* __restrict__ out, float v, int n) {
    int i = blockIdx.x * 256 + threadIdx.x;
    if (i < n) out[i] = v;
}

// ---------------- CSR build ----------------

__global__ __launch_bounds__(256) void hist2_kernel(const int* __restrict__ dst,
                                                    const int* __restrict__ batch,
                                                    int* __restrict__ hist,
                                                    int* __restrict__ ghist, int E, int N) {
    int i = blockIdx.x * 256 + threadIdx.x;
    if (i < E) atomicAdd(&hist[dst[i]], 1);
    else if (i < E + N) atomicAdd(&ghist[batch[i - E]], 1);
}

__global__ __launch_bounds__(256) void scan_tiles(const int* __restrict__ hist, int N,
                                                  int* __restrict__ rowptr,
                                                  int* __restrict__ tsum) {
    int tid = threadIdx.x;
    int i = blockIdx.x * 256 + tid;
    int v = (i < N) ? hist[i] : 0;
    __shared__ int s[256];
    s[tid] = v;
    __syncthreads();
    for (int off = 1; off < 256; off <<= 1) {
        int t = (tid >= off) ? s[tid - off] : 0;
        __syncthreads();
        s[tid] += t;
        __syncthreads();
    }
    if (i < N) rowptr[i] = s[tid] - v;
    if (tid == 255) tsum[blockIdx.x] = s[255];
}

// block 0: scan of tile sums (-> toff, total); block 1: graph-offset scan (ghist -> goff)
__global__ __launch_bounds__(256) void scan_misc(const int* __restrict__ tsum, int ntiles,
                                                 int* __restrict__ toff,
                                                 int* __restrict__ totalp,
                                                 const int* __restrict__ ghist,
                                                 int* __restrict__ goff,
                                                 int* __restrict__ gfill, int B) {
    int tid = threadIdx.x;
    if (blockIdx.x == 0) {
        int v = (tid < ntiles) ? tsum[tid] : 0;
        __shared__ int s[256];
        s[tid] = v;
        __syncthreads();
        for (int off = 1; off < 256; off <<= 1) {
            int t = (tid >= off) ? s[tid - off] : 0;
            __syncthreads();
            s[tid] += t;
            __syncthreads();
        }
        if (tid < ntiles) toff[tid] = s[tid] - v;
        if (tid == 255) *totalp = s[255];
    } else {
        int v = (tid < B) ? ghist[tid] : 0;
        __shared__ int s2[256];
        s2[tid] = v;
        __syncthreads();
        for (int off = 1; off < 256; off <<= 1) {
            int t = (tid >= off) ? s2[tid - off] : 0;
            __syncthreads();
            s2[tid] += t;
            __syncthreads();
        }
        if (tid < B) {
            goff[tid] = s2[tid] - v;
            gfill[tid] = s2[tid] - v;
        }
        if (tid == 255) goff[B] = s2[255];
    }
}

__global__ __launch_bounds__(256) void scan_apply(int* __restrict__ rowptr,
                                                  const int* __restrict__ toff, int N,
                                                  int* __restrict__ fill) {
    int i = blockIdx.x * 256 + threadIdx.x;
    if (i < N) {
        int r = rowptr[i] + toff[blockIdx.x];
        rowptr[i] = r;
        fill[i] = r;
    }
}

__global__ __launch_bounds__(256) void scatter_kernel(const int* __restrict__ src,
                                                      const int* __restrict__ dst,
                                                      int* __restrict__ fill,
                                                      int* __restrict__ srcs, int E) {
    int e = blockIdx.x * 256 + threadIdx.x;
    if (e < E) {
        int p = atomicAdd(&fill[dst[e]], 1);
        srcs[p] = src[e];
    }
}

// ---------------- GENConv aggregation -> bf16 A-operand (K-padded), VEC feats/thread ------

template <typename T, int VEC>
__global__ __launch_bounds__(256) void agg_kernel(const T* __restrict__ x,
                                                  const int* __restrict__ rowptr,
                                                  const int* __restrict__ srcs,
                                                  u16* __restrict__ out, int d, int ldx,
                                                  int Kp, int N) {
    int n = blockIdx.y * 4 + (threadIdx.x >> 6);
    int f0 = (blockIdx.x * 64 + (threadIdx.x & 63)) * VEC;
    if (n >= N || f0 >= Kp) return;
    size_t o = (size_t)n * Kp + f0;
    if (f0 >= d) {
#pragma unroll
        for (int i = 0; i < VEC; i++) out[o + i] = 0;
        return;
    }
    auto loadV = [&](const T* row, float* v) {
        if constexpr (sizeof(T) == 4) {
            float2 t = *reinterpret_cast<const float2*>(row);
            v[0] = t.x; v[1] = t.y;
        } else if constexpr (VEC == 2) {
            unsigned int u = *reinterpret_cast<const unsigned int*>(row);
            v[0] = b2fu((u16)(u & 0xffff)); v[1] = b2fu((u16)(u >> 16));
        } else if constexpr (VEC == 4) {
            uint2 u = *reinterpret_cast<const uint2*>(row);
            v[0] = b2fu((u16)(u.x & 0xffff)); v[1] = b2fu((u16)(u.x >> 16));
            v[2] = b2fu((u16)(u.y & 0xffff)); v[3] = b2fu((u16)(u.y >> 16));
        } else {
            uint4 u = *reinterpret_cast<const uint4*>(row);
            v[0] = b2fu((u16)(u.x & 0xffff)); v[1] = b2fu((u16)(u.x >> 16));
            v[2] = b2fu((u16)(u.y & 0xffff)); v[3] = b2fu((u16)(u.y >> 16));
            v[4] = b2fu((u16)(u.z & 0xffff)); v[5] = b2fu((u16)(u.z >> 16));
            v[6] = b2fu((u16)(u.w & 0xffff)); v[7] = b2fu((u16)(u.w >> 16));
        }
    };
    int e0 = rowptr[n], e1 = rowptr[n + 1];
    float s[VEC] = {}, t[VEC] = {};
    for (int e = e0; e < e1; e++) {
        int sr = srcs[e];
        float v[VEC];
        loadV(x + (size_t)sr * ldx + f0, v);
#pragma unroll
        for (int i = 0; i < VEC; i++) {
            float m = fmaxf(v[i], 0.f) + 1e-7f;
            float wv = __expf(m);
            s[i] += wv;
            t[i] += m * wv;
        }
    }
    float xs[VEC];
    loadV(x + (size_t)n * ldx + f0, xs);
    u16 ob[VEC];
#pragma unroll
    for (int i = 0; i < VEC; i++) {
        float a = t[i] / (s[i] + 1e-16f) + xs[i];
        ob[i] = (f0 + i < d) ? f2bu(a) : (u16)0;
    }
    if constexpr (VEC == 2) {
        *reinterpret_cast<unsigned int*>(out + o) =
            (unsigned int)ob[0] | ((unsigned int)ob[1] << 16);
    } else if constexpr (VEC == 4) {
        uint2 u;
        u.x = (unsigned int)ob[0] | ((unsigned int)ob[1] << 16);
        u.y = (unsigned int)ob[2] | ((unsigned int)ob[3] << 16);
        *reinterpret_cast<uint2*>(out + o) = u;
    } else {
        uint4 u;
        u.x = (unsigned int)ob[0] | ((unsigned int)ob[1] << 16);
        u.y = (unsigned int)ob[2] | ((unsigned int)ob[3] << 16);
        u.z = (unsigned int)ob[4] | ((unsigned int)ob[5] << 16);
        u.w = (unsigned int)ob[6] | ((unsigned int)ob[7] << 16);
        *reinterpret_cast<uint4*>(out + o) = u;
    }
}

// ---------------- batched weight transpose+cvt: W[K,N] f32 -> WT[Np,Kp] bf16 ----------------

struct WtJobs {
    const float* W[6];
    u16* WT[6];
    int K[6], N[6], Kp[6], Np[6];
};

__global__ __launch_bounds__(256) void wt_cvt6(WtJobs jb) {
    int jz = blockIdx.z;
    int Kp = jb.Kp[jz], Np = jb.Np[jz];
    int n = blockIdx.y * 4 + (threadIdx.x >> 6);
    int k = blockIdx.x * 64 + (threadIdx.x & 63);
    if (n >= Np || k >= Kp) return;
    int K = jb.K[jz], N = jb.N[jz];
    float v = (n < N && k < K) ? jb.W[jz][(size_t)k * N + n] : 0.f;
    jb.WT[jz][(size_t)n * Kp + k] = f2bu(v);
}

// ---------------- MFMA GEMM, fused variants ----------------
// Tile 128(M) x 64(N), BK=32, 4 waves: wave w owns rows [w*32, w*32+32) x all 64 cols.
// acc[2][4] (32 AGPR, was 64) + 24 KB LDS -> ~4 blocks/CU resident (was 2): the TLP
// that hides the per-iteration load latency. XCD swizzle; 2 LDS buffers; minimal
// 2-phase loop. Column 16B-slots XOR-swizzled by sigma(row)=((row>>1)&3) on both
// sides (inverse-swizzled global source + swizzled ds_read); sigma invariant under
// +16/+32 row strides used by fragments.
// AMODE 0: A staged via global_load_lds.  AMODE 1: A reg-staged with BN+relu applied
//   in-flight; scale/shift computed in-kernel from sum/sumsq/gamma/beta (bn_final).
// EMODE 0: bias [+relu]; zero-fills pad cols Ncols<=n<ldc.
// EMODE 1: BN-stats epilogue: K-padded C + per-column sum/sumsq atomics.
// EMODE 2: split-K atomicAdd (C float, zero-init); K-slice = blockIdx.y * kLen.

template <int AMODE, int EMODE, bool RELU, typename CT>
__global__ __launch_bounds__(256) void gemm_mfma(const u16* __restrict__ A,
                                                 const u16* __restrict__ BT,
                                                 const float* __restrict__ bias,
                                                 CT* __restrict__ C, int ldc, int M, int Ncols,
                                                 int Kp, int kLen, int nbx, int nby, int spx,
                                                 const float* __restrict__ bnsum,
                                                 const float* __restrict__ bnsumsq,
                                                 const float* __restrict__ gamma,
                                                 const float* __restrict__ beta,
                                                 float invN, int dhBN,
                                                 float* __restrict__ osum,
                                                 float* __restrict__ osumsq) {
    int xcd = blockIdx.x & 7;
    int j = blockIdx.x >> 3;
    int bx = j % nbx;
    int by = xcd * spx + j / nbx;
    if (by >= nby) return;
    __shared__ u16 As[2][128 * 32];   // 16 KB
    __shared__ u16 Bs[2][64 * 32];    //  8 KB
    __shared__ float scl[AMODE == 1 ? 640 : 1];
    __shared__ float shf[AMODE == 1 ? 640 : 1];
    const int tid = threadIdx.x;
    const int lane = tid & 63;
    const int w = tid >> 6;
    const int bm = by * 128;
    const int bn = bx * 64;
    const int kw = blockIdx.y * kLen;  // K-slice base (split-K); 0 otherwise
    f32x4 acc[2][4] = {};

    if constexpr (AMODE == 1) {  // in-kernel bn_final (redundant per block, trivial)
        for (int i = tid; i < Kp; i += 256) {
            float sc = 0.f, sh = 0.f;
            if (i < dhBN) {
                float mu = bnsum[i] * invN;
                float var = bnsumsq[i] * invN - mu * mu;
                sc = gamma[i] / sqrtf(var + 1e-5f);
                sh = beta[i] - mu * sc;
            }
            scl[i] = sc;
            shf[i] = sh;
        }
        __syncthreads();
    }

    // staging: wave w instr covers rows [w*16, w*16+16); A has a 2nd instr at +64.
    // lane l -> row base+(l>>2), stored 16B-slot (l&3); source col = slot ^ sigma(row)
    const int r0 = w * 16 + (lane >> 2);
    const int r1 = r0 + 64;                       // sigma(r1) == sigma(r0)
    const int sw = ((lane & 3) ^ ((r0 >> 1) & 3)) << 3;  // u16 offset of source col
    const u16* Ag0 = A + (size_t)(bm + r0) * Kp + sw + kw;
    const u16* Ag1 = A + (size_t)(bm + r1) * Kp + sw + kw;
    const u16* Bg0 = BT + (size_t)(bn + r0) * Kp + sw + kw;
    const int wb = w << 9;  // wave LDS base (u16): w*16 rows * 32 cols

    uint4 a0r, a1r;  // AMODE1 in-flight A regs
    auto stageB = [&](int b, int koff) { gload16(Bg0 + koff, &Bs[b][wb]); };
    auto stageA_lds = [&](int b, int koff) {
        gload16(Ag0 + koff, &As[b][wb]);
        gload16(Ag1 + koff, &As[b][2048 + wb]);
    };
    auto loadA_reg = [&](int koff) {
        a0r = *reinterpret_cast<const uint4*>(Ag0 + koff);
        a1r = *reinterpret_cast<const uint4*>(Ag1 + koff);
    };
    auto writeA_reg = [&](int b, int koff) {
        int f0 = sw + kw + koff;  // feature (=source col) index of this lane's 8 elems
        float4 sc0 = *reinterpret_cast<const float4*>(&scl[f0]);
        float4 sc1 = *reinterpret_cast<const float4*>(&scl[f0 + 4]);
        float4 sh0 = *reinterpret_cast<const float4*>(&shf[f0]);
        float4 sh1 = *reinterpret_cast<const float4*>(&shf[f0 + 4]);
        auto tf2 = [](unsigned int u, float sa, float sb, float ha, float hb) {
            float h0 = b2fu((u16)(u & 0xffff)), h1 = b2fu((u16)(u >> 16));
            float v0 = fmaxf(fmaf(h0, sa, ha), 0.f);
            float v1 = fmaxf(fmaf(h1, sb, hb), 0.f);
            return (unsigned int)f2bu(v0) | ((unsigned int)f2bu(v1) << 16);
        };
        uint4 o0, o1;
        o0.x = tf2(a0r.x, sc0.x, sc0.y, sh0.x, sh0.y);
        o0.y = tf2(a0r.y, sc0.z, sc0.w, sh0.z, sh0.w);
        o0.z = tf2(a0r.z, sc1.x, sc1.y, sh1.x, sh1.y);
        o0.w = tf2(a0r.w, sc1.z, sc1.w, sh1.z, sh1.w);
        o1.x = tf2(a1r.x, sc0.x, sc0.y, sh0.x, sh0.y);
        o1.y = tf2(a1r.y, sc0.z, sc0.w, sh0.z, sh0.w);
        o1.z = tf2(a1r.z, sc1.x, sc1.y, sh1.x, sh1.y);
        o1.w = tf2(a1r.w, sc1.z, sc1.w, sh1.z, sh1.w);
        *reinterpret_cast<uint4*>(&As[b][wb + lane * 8]) = o0;
        *reinterpret_cast<uint4*>(&As[b][2048 + wb + lane * 8]) = o1;
    };

    // fragment read geometry (XOR involution cancels against the staged layout)
    const int fm = w * 32 + (lane & 15);   // + mt*16, mt in {0,1}
    const int fn = lane & 15;              // + nt*16, nt in {0..3}
    const int g = lane >> 4;
    const int ka = (g ^ ((fm >> 1) & 3)) << 3;  // sigma invariant across mt*16
    const int kb = (g ^ ((fn >> 1) & 3)) << 3;  // sigma invariant across nt*16

    const int nk = kLen >> 5;
    // prologue: stage tile 0, drain, barrier
    if constexpr (AMODE == 0) {
        stageA_lds(0, 0);
        stageB(0, 0);
        asm volatile("s_waitcnt vmcnt(0)" ::: "memory");
    } else {
        loadA_reg(0);
        stageB(0, 0);
        asm volatile("s_waitcnt vmcnt(0)" ::: "memory");
        writeA_reg(0, 0);
        asm volatile("s_waitcnt lgkmcnt(0)" ::: "memory");
    }
    __builtin_amdgcn_s_barrier();
    for (int k = 0; k < nk; k++) {
        const int cur = k & 1;
        if (k + 1 < nk) {  // prefetch next tile
            if constexpr (AMODE == 0) stageA_lds(cur ^ 1, (k + 1) << 5);
            else loadA_reg((k + 1) << 5);
            stageB(cur ^ 1, (k + 1) << 5);
        }
        bh8 af[2], bf[4];
#pragma unroll
        for (int mt = 0; mt < 2; mt++)
            af[mt] = *reinterpret_cast<const bh8*>(&As[cur][(fm + mt * 16) * 32 + ka]);
#pragma unroll
        for (int nt = 0; nt < 4; nt++)
            bf[nt] = *reinterpret_cast<const bh8*>(&Bs[cur][(fn + nt * 16) * 32 + kb]);
        asm volatile("s_waitcnt lgkmcnt(0)" ::: "memory");
        __builtin_amdgcn_sched_barrier(0);  // rule #18: don't hoist MFMA above the wait
        __builtin_amdgcn_s_setprio(1);
#pragma unroll
        for (int mt = 0; mt < 2; mt++)
#pragma unroll
            for (int nt = 0; nt < 4; nt++)
                acc[mt][nt] = __builtin_amdgcn_mfma_f32_16x16x32_bf16(af[mt], bf[nt],
                                                                      acc[mt][nt], 0, 0, 0);
        __builtin_amdgcn_s_setprio(0);
        __builtin_amdgcn_sched_barrier(0);  // keep MFMAs above the drain
        asm volatile("s_waitcnt vmcnt(0)" ::: "memory");  // next tile's loads landed
        if constexpr (AMODE == 1) {
            __builtin_amdgcn_sched_barrier(0);
            if (k + 1 < nk) writeA_reg(cur ^ 1, (k + 1) << 5);
            asm volatile("s_waitcnt lgkmcnt(0)" ::: "memory");  // ds_writes visible
        }
        __builtin_amdgcn_s_barrier();  // all waves: reads of cur done, nxt ready
    }
    const int rq = (lane >> 4) * 4;
    const int cl = lane & 15;
    if constexpr (EMODE == 0) {
#pragma unroll
        for (int mt = 0; mt < 2; mt++) {
#pragma unroll
            for (int nt = 0; nt < 4; nt++) {
                int n = bn + nt * 16 + cl;
                if (n >= ldc) continue;
                bool valid = (n < Ncols);
                float bv = valid ? bias[n] : 0.f;
#pragma unroll
                for (int r = 0; r < 4; r++) {
                    int m = bm + w * 32 + mt * 16 + rq + r;
                    if (m >= M) continue;
                    float v = valid ? acc[mt][nt][r] + bv : 0.f;
                    if (RELU) v = fmaxf(v, 0.f);
                    if (sizeof(CT) == 2)
                        C[(size_t)m * ldc + n] = (CT)f2bu(v);
                    else
                        C[(size_t)m * ldc + n] = (CT)v;
                }
            }
        }
    } else if constexpr (EMODE == 1) {
        // BN-stats epilogue
        float cs[4] = {0.f, 0.f, 0.f, 0.f}, cq[4] = {0.f, 0.f, 0.f, 0.f};
#pragma unroll
        for (int nt = 0; nt < 4; nt++) {
            int n = bn + nt * 16 + cl;
            if (n >= ldc) continue;
            float bv = (n < Ncols) ? bias[n] : 0.f;
#pragma unroll
            for (int mt = 0; mt < 2; mt++) {
#pragma unroll
                for (int r = 0; r < 4; r++) {
                    int m = bm + w * 32 + mt * 16 + rq + r;
                    if (m >= M) continue;
                    float v = (n < Ncols) ? acc[mt][nt][r] + bv : 0.f;
                    C[(size_t)m * ldc + n] = (CT)f2bu(v);
                    cs[nt] += v;
                    cq[nt] += v * v;
                }
            }
        }
        float* red = (float*)&As[0][0];  // 64 cols x 16 slots x {sum,sq} = 8 KB
        const int slot = w * 4 + (lane >> 4);
#pragma unroll
        for (int nt = 0; nt < 4; nt++) {
            int nl = nt * 16 + cl;
            red[nl * 16 + slot] = cs[nt];
            red[1024 + nl * 16 + slot] = cq[nt];
        }
        __syncthreads();
        if (tid < 64) {
            int n = bn + tid;
            if (n < Ncols) {
                float s = 0.f, q = 0.f;
#pragma unroll
                for (int i = 0; i < 16; i++) {
                    s += red[tid * 16 + i];
                    q += red[1024 + tid * 16 + i];
                }
                atomicAdd(&osum[n], s);
                atomicAdd(&osumsq[n], q);
            }
        }
    } else {
        // split-K: atomic accumulate into zero-initialized float C (no bias)
#pragma unroll
        for (int mt = 0; mt < 2; mt++) {
#pragma unroll
            for (int nt = 0; nt < 4; nt++) {
                int n = bn + nt * 16 + cl;
                if (n >= Ncols) continue;
#pragma unroll
                for (int r = 0; r < 4; r++) {
                    int m = bm + w * 32 + mt * 16 + rq + r;
                    if (m >= M) continue;
                    atomicAdd((float*)&C[(size_t)m * ldc + n], acc[mt][nt][r]);
                }
            }
        }
    }
}

// ---------------- segmented global mean pool (batch sorted) ----------------

__global__ __launch_bounds__(256) void pool_seg(const u16* __restrict__ h,
                                                const int* __restrict__ goff,
                                                float* __restrict__ gsum, int d) {
    int g = blockIdx.y;
    int c = threadIdx.x & 63;
    int f = blockIdx.x * 64 + c;
    int wv = threadIdx.x >> 6;
    int r0 = goff[g], r1 = goff[g + 1];
    float s = 0.f;
    if (f < d)
        for (int r = r0 + wv; r < r1; r += 4) s += b2fu(h[(size_t)r * d + f]);
    __shared__ float ls[4][64];
    ls[wv][c] = s;
    __syncthreads();
    if (wv == 0 && f < d) {
        float tot = ls[0][c] + ls[1][c] + ls[2][c] + ls[3][c];
        gsum[(size_t)g * d + f] = tot / fmaxf((float)(r1 - r0), 1.f);
    }
}

// ---------------- split-K GEMM for small-M FC chain (f32) ----------------
// C pre-filled with bias; relu applied to A elements with k < klim.

__global__ __launch_bounds__(256) void gemm_sk(const float* __restrict__ A, int lda,
                                               const float* __restrict__ B, int ldb,
                                               float* __restrict__ C, int ldc, int M, int K,
                                               int Nn, int KC, int klim) {
    __shared__ float As[16][17];
    __shared__ float Bs[16][68];
    const int tid = threadIdx.x;
    const int bn = blockIdx.x * 64;
    const int bm = blockIdx.y * 16;
    const int k0 = blockIdx.z * KC;
    const int kend = min(K, k0 + KC);
    const int tx = tid & 63;
    const int ty = tid >> 6;
    float acc[4] = {};
    const int am = bm + (tid >> 4);
    const int ak = tid & 15;
    for (int kk0 = k0; kk0 < kend; kk0 += 16) {
        {
            int k = kk0 + ak;
            float v = (am < M && k < kend) ? A[(size_t)am * lda + k] : 0.f;
            if (k < klim) v = fmaxf(v, 0.f);
            As[ak][tid >> 4] = v;
        }
#pragma unroll
        for (int i = 0; i < 4; i++) {
            int k = kk0 + ty + 4 * i;
            Bs[ty + 4 * i][tx] = (k < kend && bn + tx < Nn) ? B[(size_t)k * ldb + bn + tx] : 0.f;
        }
        __syncthreads();
#pragma unroll
        for (int kk = 0; kk < 16; kk++) {
            float b = Bs[kk][tx];
#pragma unroll
            for (int i = 0; i < 4; i++) acc[i] = fmaf(As[kk][ty + 4 * i], b, acc[i]);
        }
        __syncthreads();
    }
    if (bn + tx < Nn) {
#pragma unroll
        for (int i = 0; i < 4; i++) {
            int m = bm + ty + 4 * i;
            if (m < M) atomicAdd(&C[(size_t)m * ldc + bn + tx], acc[i]);
        }
    }
}

static void launch_gemm_small(const float* A, int lda, const float* B, int ldb,
                              float* C, int ldc, int M, int K, int Nn, int klim,
                              hipStream_t stream) {
    int gx = (Nn + 63) / 64, gy = (M + 15) / 16;
    int tiles = gx * gy;
    int ksplit = 512 / tiles;
    if (ksplit < 1) ksplit = 1;
    int maxsplit = (K + 63) / 64;
    if (ksplit > maxsplit) ksplit = maxsplit;
    int KC = (((K + ksplit - 1) / ksplit) + 15) & ~15;
    ksplit = (K + KC - 1) / KC;
    gemm_sk<<<dim3(gx, gy, ksplit), 256, 0, stream>>>(A, lda, B, ldb, C, ldc, M, K, Nn, KC,
                                                      klim);
}

// ---------------- batched bias prefill for FC output buffers ----------------

struct FillJobs {
    float* C[6];
    const float* b[6];
    int ld[6], n0[6], n1[6];
};

__global__ __launch_bounds__(256) void prefill6(FillJobs jb, int M) {
    int jz = blockIdx.z;
    int w = jb.n1[jz] - jb.n0[jz];
    int i = blockIdx.x * 256 + threadIdx.x;
    if (i >= M * w) return;
    int m = i / w, n = i - m * w;
    jb.C[jz][(size_t)m * jb.ld[jz] + jb.n0[jz] + n] = jb.b[jz][n];
}

// ---------------- protein branch as GEMM (round-6 structure, measured fast) ----------------
// S[(b*26+t), (o*8+k)] = sum_i [target[b,i]==t] * cw[o,i,k]  ==  H @ cwT

__global__ __launch_bounds__(256) void hone_kernel(const int* __restrict__ target,
                                                   u16* __restrict__ H, int total) {
    int i = blockIdx.x * 256 + threadIdx.x;
    if (i >= total) return;
    int b = i / 1000, pos = i - b * 1000;
    int t = target[i];
    H[((size_t)b * 26 + t) * 1024 + pos] = 0x3F80;  // bf16(1.0)
}

__global__ __launch_bounds__(256) void cwt_cvt(const float* __restrict__ cw,
                                               u16* __restrict__ BT) {
    int n = blockIdx.y;                           // 256
    int kk = blockIdx.x * 256 + threadIdx.x;      // 1024
    int o = n >> 3, k = n & 7;
    float v = (kk < 1000) ? cw[(size_t)o * 8000 + (size_t)kk * 8 + k] : 0.f;
    BT[(size_t)n * 1024 + kk] = f2bu(v);
}

// conv[b,o,w] = cb[o] + sum_t sum_k S[b*6656 + t*256 + o*8+k] * emb[t*128 + w+k]
__global__ __launch_bounds__(256) void prot_conv_kernel(const float* __restrict__ S,
                                                        const float* __restrict__ emb,
                                                        const float* __restrict__ cb,
                                                        float* __restrict__ out) {
    int b = blockIdx.x;
    int tid = threadIdx.x;
    __shared__ float Sl[6656];
    __shared__ float el[26 * 128];
    for (int i = tid; i < 6656; i += 256) Sl[i] = S[(size_t)b * 6656 + i];
    for (int i = tid; i < 26 * 128; i += 256) el[i] = emb[i];
    __syncthreads();
    for (int j = tid; j < 3872; j += 256) {
        int o = j / 121;
        int w = j - o * 121;
        float acc = cb[o];
        for (int t = 0; t < 26; t++) {
#pragma unroll
            for (int k = 0; k < 8; k++)
                acc = fmaf(Sl[t * 256 + o * 8 + k], el[t * 128 + w + k], acc);
        }
        out[(size_t)b * 3872 + j] = acc;
    }
}

// ---------------- final matvec (relu on A load) ----------------

__global__ __launch_bounds__(256) void out_kernel(const float* __restrict__ A,
                                                  const float* __restrict__ w,
                                                  const float* __restrict__ bias,
                                                  float* __restrict__ out, int M, int K) {
    int wave = threadIdx.x >> 6;
    int lane = threadIdx.x & 63;
    int r = blockIdx.x * 4 + wave;
    if (r >= M) return;
    float acc = 0.f;
    for (int k = lane; k < K; k += 64) acc += fmaxf(A[(size_t)r * K + k], 0.f) * w[k];
    for (int off = 32; off > 0; off >>= 1) acc += __shfl_down(acc, off, 64);
    if (lane == 0) out[r] = acc + bias[0];
}

// ---------------- host orchestration ----------------

static inline int KP(int k) { return (k + 31) & ~31; }
static inline int NP64(int n) { return (n + 63) & ~63; }
static inline int LD8(int n) { return (n + 7) & ~7; }

extern "C" void kernel_launch(void* const* d_in, const int* in_sizes, int n_in, void* d_out,
                              int out_size, void* d_ws, size_t ws_size, hipStream_t stream) {
    static const int exp_sizes[39] = {
        2340000, 300000, 30000, 256000,
        12168, 156, 156, 156, 12168, 78,
        12168, 156, 156, 156, 48672, 312,
        194688, 624, 624, 624, 389376, 624,
        319488, 512, 524288, 1024, 131072, 128,
        3328, 256000, 32, 495616, 128,
        262144, 1024, 524288, 512, 512, 1};
    int bad = (n_in != 39) ? 100 : -1;
    if (bad < 0)
        for (int i = 0; i < 39; i++)
            if (in_sizes[i] != exp_sizes[i]) { bad = i; break; }
    if (bad >= 0) {
        const_out_kernel<<<1, 256, 0, stream>>>((float*)d_out, 2048.f + 8.f * bad, out_size);
        return;
    }

    const int N = 30000, E = 150000, B = 256;
    const int Mp = 30080;   // 235*128
    const int nby = 235, spx = 30;
    const int ntiles = (N + 255) / 256;  // 118
    const float* x_in = (const float*)d_in[0];
    const int* ei = (const int*)d_in[1];
    const int* src = ei;
    const int* dst = ei + E;
    const int* batch = (const int*)d_in[2];
    const int* target = (const int*)d_in[3];

    char* p = (char*)d_ws;
    auto carve = [&](size_t bytes) {
        char* r = p;
        p += (bytes + 15) & ~(size_t)15;
        return r;
    };
    // hist + ghist + per-layer BN sums: one contiguous zero region
    int* hist = (int*)carve((size_t)(N + B) * 4 + 3 * 1280 * 4);
    int* ghist = hist + N;
    float* sums = (float*)(hist + N + B);  // 3 layers x {sum[640], sumsq[640]}
    const size_t zero_bytes = (size_t)(N + B) * 4 + 3 * 1280 * 4;
    int* rowptr = (int*)carve((size_t)(N + 1) * 4);
    int* fill = (int*)carve((size_t)N * 4);
    int* srcs = (int*)carve((size_t)E * 4);
    int* goff = (int*)carve((size_t)(B + 1) * 4);
    int* gfill = (int*)carve((size_t)B * 4);
    int* tsum = (int*)carve(256 * 4);
    int* toff = (int*)carve(256 * 4);
    float* gsum = (float*)carve((size_t)B * 624 * 4);
    float* fc1 = (float*)carve((size_t)B * 512 * 4);
    float* fc2 = (float*)carve((size_t)B * 1024 * 4);
    float* xc = (float*)carve((size_t)B * 256 * 4);
    float* fcc1 = (float*)carve((size_t)B * 1024 * 4);
    float* fcc2 = (float*)carve((size_t)B * 512 * 4);
    float* Sbuf = (float*)carve((size_t)B * 6656 * 4);
    float* convb = (float*)carve((size_t)B * 3872 * 4);
    u16* Hbuf = (u16*)carve((size_t)B * 26 * 1024 * 2);  // one-hot, 13.6 MB
    u16* cwT = (u16*)carve((size_t)256 * 1024 * 2);
    u16* Abf = (u16*)carve((size_t)Mp * 640 * 2);
    u16* hmidb = (u16*)carve((size_t)Mp * 640 * 2);   // K-padded h (GEMM2 A operand)
    u16* Lout = (u16*)carve((size_t)N * 624 * 2);
    struct Layer { int di, dh, dn, w1, b1, g, be, w2, b2; };
    const Layer L[3] = {
        {78, 156, 78, 4, 5, 6, 7, 8, 9},
        {78, 156, 312, 10, 11, 12, 13, 14, 15},
        {312, 624, 624, 16, 17, 18, 19, 20, 21},
    };
    u16* WT1[3];
    u16* WT2[3];
    for (int li = 0; li < 3; li++) {
        WT1[li] = (u16*)carve((size_t)NP64(L[li].dh) * KP(L[li].di) * 2);
        WT2[li] = (u16*)carve((size_t)NP64(L[li].dn) * KP(L[li].dh) * 2);
    }
    size_t need = (size_t)(p - (char*)d_ws);
    if (ws_size < need) {
        const_out_kernel<<<1, 256, 0, stream>>>((float*)d_out,
                                                1024.f + (float)(ws_size >> 20), out_size);
        return;
    }

    // ---- CSR by dst (hierarchical scan) + graph offsets ----
    hipMemsetAsync(hist, 0, zero_bytes, stream);
    hist2_kernel<<<(E + N + 255) / 256, 256, 0, stream>>>(dst, batch, hist, ghist, E, N);
    scan_tiles<<<ntiles, 256, 0, stream>>>(hist, N, rowptr, tsum);
    scan_misc<<<2, 256, 0, stream>>>(tsum, ntiles, toff, rowptr + N, ghist, goff, gfill, B);
    scan_apply<<<ntiles, 256, 0, stream>>>(rowptr, toff, N, fill);
    scatter_kernel<<<(E + 255) / 256, 256, 0, stream>>>(src, dst, fill, srcs, E);

    // ---- weight transpose+cvt (single batched dispatch) ----
    {
        WtJobs jb;
        int mgx = 1, mgy = 1;
        for (int li = 0; li < 3; li++) {
            jb.W[2 * li] = (const float*)d_in[L[li].w1];
            jb.WT[2 * li] = WT1[li];
            jb.K[2 * li] = L[li].di; jb.N[2 * li] = L[li].dh;
            jb.Kp[2 * li] = KP(L[li].di); jb.Np[2 * li] = NP64(L[li].dh);
            jb.W[2 * li + 1] = (const float*)d_in[L[li].w2];
            jb.WT[2 * li + 1] = WT2[li];
            jb.K[2 * li + 1] = L[li].dh; jb.N[2 * li + 1] = L[li].dn;
            jb.Kp[2 * li + 1] = KP(L[li].dh); jb.Np[2 * li + 1] = NP64(L[li].dn);
        }
        for (int i = 0; i < 6; i++) {
            int gx = (jb.Kp[i] + 63) / 64, gy = (jb.Np[i] + 3) / 4;
            if (gx > mgx) mgx = gx;
            if (gy > mgy) mgy = gy;
        }
        wt_cvt6<<<dim3(mgx, mgy, 6), 256, 0, stream>>>(jb);
    }

    // ---- GENConv layers (BN stats fused into GEMM1, bn_final+BN apply fused into GEMM2) --
    const int ldo[3] = {LD8(L[0].dn), LD8(L[1].dn), LD8(L[2].dn)};  // 80, 312, 624
    for (int li = 0; li < 3; li++) {
        const int di = L[li].di, dh = L[li].dh, dn = L[li].dn;
        const int Kp1 = KP(di), Kp2 = KP(dh);
        float* sumL = sums + li * 1280;
        float* sumsqL = sumL + 640;
        if (li == 0)
            agg_kernel<float, 2><<<dim3((Kp1 / 2 + 63) / 64, (N + 3) / 4), 256, 0, stream>>>(
                x_in, rowptr, srcs, Abf, di, di, Kp1, N);
        else if (li == 1)
            agg_kernel<u16, 4><<<dim3((Kp1 / 4 + 63) / 64, (N + 3) / 4), 256, 0, stream>>>(
                Lout, rowptr, srcs, Abf, di, ldo[0], Kp1, N);
        else
            agg_kernel<u16, 8><<<dim3((Kp1 / 8 + 63) / 64, (N + 3) / 4), 256, 0, stream>>>(
                Lout, rowptr, srcs, Abf, di, ldo[1], Kp1, N);
        {
            // h = Abf @ W1 + b1 -> hmidb (ldc = Kp2, zero-padded cols) + column stats
            int nbx = (Kp2 + 63) / 64;  // covers ldc; B rows <= NP64(dh)
            gemm_mfma<0, 1, false, u16><<<dim3(8 * spx * nbx), 256, 0, stream>>>(
                Abf, WT1[li], (const float*)d_in[L[li].b1], hmidb, Kp2, N, dh, Kp1, Kp1, nbx,
                nby, spx, nullptr, nullptr, nullptr, nullptr, 0.f, 0, sumL, sumsqL);
        }
        {
            // Lout = relu(bn(h)) @ W2 + b2; scale/shift computed in-kernel from stats
            int nbx = (ldo[li] + 63) / 64;  // covers ldc; B rows <= NP64(dn)
            gemm_mfma<1, 0, true, u16><<<dim3(8 * spx * nbx), 256, 0, stream>>>(
                hmidb, WT2[li], (const float*)d_in[L[li].b2], Lout, ldo[li], N, dn, Kp2, Kp2,
                nbx, nby, spx, sumL, sumsqL, (const float*)d_in[L[li].g],
                (const float*)d_in[L[li].be], 1.0f / N, dh, nullptr, nullptr);
        }
    }

    // ---- segmented global mean pool (Lout stride 624 == d) ----
    pool_seg<<<dim3(10, B), 256, 0, stream>>>(Lout, goff, gsum, 624);

    // ---- FC output buffers: prefill with bias ----
    {
        FillJobs fj;
        fj.C[0] = fc1;  fj.b[0] = (const float*)d_in[23]; fj.ld[0] = 512;  fj.n0[0] = 0;   fj.n1[0] = 512;
        fj.C[1] = fc2;  fj.b[1] = (const float*)d_in[25]; fj.ld[1] = 1024; fj.n0[1] = 0;   fj.n1[1] = 1024;
        fj.C[2] = xc;   fj.b[2] = (const float*)d_in[27]; fj.ld[2] = 256;  fj.n0[2] = 0;   fj.n1[2] = 128;
        fj.C[3] = xc;   fj.b[3] = (const float*)d_in[32]; fj.ld[3] = 256;  fj.n0[3] = 128; fj.n1[3] = 256;
        fj.C[4] = fcc1; fj.b[4] = (const float*)d_in[34]; fj.ld[4] = 1024; fj.n0[4] = 0;   fj.n1[4] = 1024;
        fj.C[5] = fcc2; fj.b[5] = (const float*)d_in[36]; fj.ld[5] = 512;  fj.n0[5] = 0;   fj.n1[5] = 512;
        prefill6<<<dim3((B * 1024 + 255) / 256, 1, 6), 256, 0, stream>>>(fj, B);
    }

    // ---- protein branch: S = H @ cwT via split-K MFMA, then conv (round-6 path) ----
    hipMemsetAsync(Hbuf, 0, (size_t)B * 26 * 1024 * 2, stream);
    hipMemsetAsync(Sbuf, 0, (size_t)B * 6656 * 4, stream);
    hone_kernel<<<(B * 1000 + 255) / 256, 256, 0, stream>>>(target, Hbuf, B * 1000);
    cwt_cvt<<<dim3(4, 256), 256, 0, stream>>>((const float*)d_in[29], cwT);
    {
        // M = B*26 = 6656 = 52*128, N = 256 (4 x 64-tiles), Kp = 1024, split-K x4
        int nbxS = 4, nbyS = 52, spxS = 7;
        gemm_mfma<0, 2, false, float><<<dim3(8 * spxS * nbxS, 4), 256, 0, stream>>>(
            Hbuf, cwT, nullptr, Sbuf, 256, 6656, 256, 1024, 256, nbxS, nbyS, spxS, nullptr,
            nullptr, nullptr, nullptr, 0.f, 0, nullptr, nullptr);
    }
    prot_conv_kernel<<<B, 256, 0, stream>>>(Sbuf, (const float*)d_in[28],
                                            (const float*)d_in[30], convb);
    launch_gemm_small(convb, 3872, (const float*)d_in[31], 128, xc + 128, 256, B, 3872, 128, 0,
                      stream);  // xc[:, 128:]

    // ---- graph FC chain (relu on consumer A-load via klim) ----
    launch_gemm_small(gsum, 624, (const float*)d_in[22], 512, fc1, 512, B, 624, 512, 0, stream);
    launch_gemm_small(fc1, 512, (const float*)d_in[24], 1024, fc2, 1024, B, 512, 1024, 512,
                      stream);
    launch_gemm_small(fc2, 1024, (const float*)d_in[26], 128, xc, 256, B, 1024, 128, 1024,
                      stream);  // xc[:, :128]

    // ---- head (f1 A = xc: relu only graph half, k < 128) ----
    launch_gemm_small(xc, 256, (const float*)d_in[33], 1024, fcc1, 1024, B, 256, 1024, 128,
                      stream);
    launch_gemm_small(fcc1, 1024, (const float*)d_in[35], 512, fcc2, 512, B, 1024, 512, 1024,
                      stream);
    out_kernel<<<(B + 3) / 4, 256, 0, stream>>>(fcc2, (const float*)d_in[37],
                                                (const float*)d_in[38], (float*)d_out, B, 512);
}